// Round 1
// baseline (1719.602 us; speedup 1.0000x reference)
//
#include <hip/hip_runtime.h>
#include <cstdint>
#include <cstddef>

#define B_ 4
#define S_ 2048
#define D_ 768
#define F_ 3072
#define E_ 8
#define NTOK (B_*S_)        // 8192
#define NASSIGN (NTOK*2)    // 16384 (every token has exactly 2 experts)

typedef unsigned short u16;
typedef __attribute__((ext_vector_type(8))) __bf16 bf16x8;
typedef __attribute__((ext_vector_type(4))) float f32x4;

__device__ __forceinline__ u16 f2bf(float f) {
    unsigned int u = __builtin_bit_cast(unsigned int, f);
    u += 0x7fffu + ((u >> 16) & 1u);   // RNE
    return (u16)(u >> 16);
}

__device__ __forceinline__ void async16(const void* g, void* l) {
    __builtin_amdgcn_global_load_lds(
        (const __attribute__((address_space(1))) unsigned int*)g,
        (__attribute__((address_space(3))) unsigned int*)l, 16, 0, 0);
}

// ---------------- init (zero accumulators/counters) ----------------
__global__ void k_init(float* usage, float* zsum, int* counts, int* cursors) {
    int t = threadIdx.x;
    if (t < E_) { usage[t] = 0.f; counts[t] = 0; cursors[t] = 0; }
    if (t == 0) *zsum = 0.f;
}

// ---------------- x fp32 -> bf16 ----------------
__global__ void k_cvt_x(const float* __restrict__ x, u16* __restrict__ xb) {
    int id = blockIdx.x * 256 + threadIdx.x;     // NTOK*D_/4 threads
    float4 v = ((const float4*)x)[id];
    ushort4 o;
    o.x = f2bf(v.x); o.y = f2bf(v.y); o.z = f2bf(v.z); o.w = f2bf(v.w);
    ((ushort4*)xb)[id] = o;
}

// ------------- weight transpose+convert: in[e][R][C] f32 -> out[e][C][R] bf16 -------------
__global__ void k_tcvt(const float* __restrict__ in, u16* __restrict__ out, int R, int C) {
    __shared__ u16 t[32][33];
    int e = blockIdx.z;
    int c0 = blockIdx.x * 32, r0 = blockIdx.y * 32;
    int tx = threadIdx.x & 31, ty = threadIdx.x >> 5;    // 32x8
    const float* ip = in + (size_t)e * R * C;
    u16* op = out + (size_t)e * C * R;
    #pragma unroll
    for (int i = 0; i < 32; i += 8)
        t[ty + i][tx] = f2bf(ip[(size_t)(r0 + ty + i) * C + (c0 + tx)]);
    __syncthreads();
    #pragma unroll
    for (int i = 0; i < 32; i += 8)
        op[(size_t)(c0 + ty + i) * R + (r0 + tx)] = t[tx][ty + i];
}

// ---------------- router: logits, softmax, top-2, losses ----------------
__global__ __launch_bounds__(256) void k_router(
    const float* __restrict__ x, const float* __restrict__ Wr,
    float* __restrict__ usage, float* __restrict__ zsum, int* __restrict__ counts,
    int* __restrict__ tk_idx, float* __restrict__ tk_w)
{
    __shared__ float wrt[E_ * D_];    // Wr transposed: [e][d], conflict-free reads
    int tid = threadIdx.x;
    for (int i = tid; i < E_ * D_; i += 256) {
        int d = i >> 3, e = i & 7;
        wrt[e * D_ + d] = Wr[i];
    }
    __syncthreads();
    int w = tid >> 6, lane = tid & 63;
    int tok = blockIdx.x * 4 + w;     // one wave per token
    float acc[E_];
    #pragma unroll
    for (int e = 0; e < E_; e++) acc[e] = 0.f;
    const float* xr = x + (size_t)tok * D_;
    for (int d = lane; d < D_; d += 64) {
        float xv = xr[d];
        #pragma unroll
        for (int e = 0; e < E_; e++) acc[e] += xv * wrt[e * D_ + d];
    }
    #pragma unroll
    for (int off = 32; off > 0; off >>= 1) {
        #pragma unroll
        for (int e = 0; e < E_; e++) acc[e] += __shfl_down(acc[e], off);
    }
    if (lane == 0) {
        float m = acc[0];
        #pragma unroll
        for (int e = 1; e < E_; e++) m = fmaxf(m, acc[e]);
        float p[E_], s = 0.f;
        #pragma unroll
        for (int e = 0; e < E_; e++) { p[e] = expf(acc[e] - m); s += p[e]; }
        float inv = 1.f / s;
        #pragma unroll
        for (int e = 0; e < E_; e++) p[e] *= inv;
        float lse = m + logf(s);
        atomicAdd(zsum, lse * lse);
        #pragma unroll
        for (int e = 0; e < E_; e++) atomicAdd(&usage[e], p[e]);
        // top-2 (earliest index wins ties, matching lax.top_k)
        int i1 = 0;
        for (int e = 1; e < E_; e++) if (p[e] > p[i1]) i1 = e;
        int i2 = -1;
        for (int e = 0; e < E_; e++) {
            if (e == i1) continue;
            if (i2 < 0 || p[e] > p[i2]) i2 = e;
        }
        float denom = p[i1] + p[i2] + 1e-8f;
        tk_idx[tok * 2 + 0] = i1; tk_idx[tok * 2 + 1] = i2;
        tk_w[tok * 2 + 0] = p[i1] / denom;
        tk_w[tok * 2 + 1] = p[i2] / denom;
        atomicAdd(&counts[i1], 1); atomicAdd(&counts[i2], 1);
    }
}

// ---------------- scan counts -> offsets, finalize scalar losses ----------------
__global__ void k_scan_finalize(const int* __restrict__ counts, int* __restrict__ offsets,
                                const float* __restrict__ usage, const float* __restrict__ zsum,
                                float* __restrict__ out_scalars)
{
    if (threadIdx.x == 0) {
        int o = 0;
        for (int e = 0; e < E_; e++) { offsets[e] = o; o += counts[e]; }
        float u[E_], mean = 0.f;
        for (int e = 0; e < E_; e++) { u[e] = usage[e] / (float)NTOK; mean += u[e]; }
        mean /= (float)E_;
        float var = 0.f;
        for (int e = 0; e < E_; e++) { float d = u[e] - mean; var += d * d; }
        var /= (float)E_;
        out_scalars[0] = var / (mean * mean + 1e-8f) * (float)E_ * 0.01f;  // lb_loss
        out_scalars[1] = (*zsum / (float)NTOK) * 0.001f;                    // z_loss
    }
}

// ---------------- build compact per-expert assignment lists ----------------
__global__ void k_fill(const int* __restrict__ tk_idx, const float* __restrict__ tk_w,
                       const int* __restrict__ offsets, int* __restrict__ cursors,
                       int* __restrict__ assign_token, float* __restrict__ assign_weight,
                       int* __restrict__ pos)
{
    int t = blockIdx.x * 256 + threadIdx.x;
    if (t >= NTOK) return;
    #pragma unroll
    for (int k = 0; k < 2; k++) {
        int e = tk_idx[t * 2 + k];
        int pz = atomicAdd(&cursors[e], 1);
        int row = offsets[e] + pz;
        assign_token[row] = t;
        assign_weight[row] = tk_w[t * 2 + k];
        pos[t * 2 + k] = row;
    }
}

// ---------------- GEMM1: h = gelu(gather(x) @ W1[e] + b1[e]), bf16 MFMA ----------------
__global__ __launch_bounds__(256) void k_gemm1(
    const u16* __restrict__ xb, const u16* __restrict__ w1t,
    const float* __restrict__ b1,
    const int* __restrict__ counts, const int* __restrict__ offsets,
    const int* __restrict__ assign_token, u16* __restrict__ h)
{
    int e = blockIdx.x >> 6;
    int mt = blockIdx.x & 63;
    int cnt = counts[e];
    int m0 = mt * 128;
    if (m0 >= cnt) return;
    int off = offsets[e];
    int n0 = blockIdx.y * 128;

    __shared__ __align__(16) u16 As[128 * 32];   // [m][k] K-major
    __shared__ __align__(16) u16 Bs[128 * 32];   // [n][k] K-major

    int tid = threadIdx.x;
    int w = tid >> 6, lane = tid & 63;
    int rA = lane >> 2;                 // row within 16-row chunk
    int colk = (lane & 3) * 8;          // k element offset within 32
    int r0 = (w * 2 + 0) * 16 + rA;
    int r1 = (w * 2 + 1) * 16 + rA;

    int g0 = m0 + r0; if (g0 > cnt - 1) g0 = cnt - 1;
    int g1 = m0 + r1; if (g1 > cnt - 1) g1 = cnt - 1;
    const u16* agp0 = xb + (size_t)assign_token[off + g0] * D_ + colk;
    const u16* agp1 = xb + (size_t)assign_token[off + g1] * D_ + colk;
    const u16* bgp0 = w1t + ((size_t)e * F_ + n0 + r0) * D_ + colk;
    const u16* bgp1 = w1t + ((size_t)e * F_ + n0 + r1) * D_ + colk;
    u16* al0 = &As[(w * 2 + 0) * 512 + lane * 8];
    u16* al1 = &As[(w * 2 + 1) * 512 + lane * 8];
    u16* bl0 = &Bs[(w * 2 + 0) * 512 + lane * 8];
    u16* bl1 = &Bs[(w * 2 + 1) * 512 + lane * 8];

    f32x4 acc[4][4];
    #pragma unroll
    for (int i = 0; i < 4; i++)
        #pragma unroll
        for (int j = 0; j < 4; j++) acc[i][j] = (f32x4){0.f, 0.f, 0.f, 0.f};

    int wm = (w >> 1) * 64, wn = (w & 1) * 64;
    int fm = lane & 15, k8 = (lane >> 4) * 8;

    for (int kk = 0; kk < D_; kk += 32) {
        async16(agp0 + kk, al0);
        async16(agp1 + kk, al1);
        async16(bgp0 + kk, bl0);
        async16(bgp1 + kk, bl1);
        __syncthreads();
        bf16x8 af[4], bfr[4];
        #pragma unroll
        for (int i = 0; i < 4; i++)
            af[i] = *(const bf16x8*)&As[(wm + i * 16 + fm) * 32 + k8];
        #pragma unroll
        for (int j = 0; j < 4; j++)
            bfr[j] = *(const bf16x8*)&Bs[(wn + j * 16 + fm) * 32 + k8];
        #pragma unroll
        for (int i = 0; i < 4; i++)
            #pragma unroll
            for (int j = 0; j < 4; j++)
                acc[i][j] = __builtin_amdgcn_mfma_f32_16x16x32_bf16(af[i], bfr[j], acc[i][j], 0, 0, 0);
        __syncthreads();
    }

    int rbase = (lane >> 4) * 4;
    #pragma unroll
    for (int j = 0; j < 4; j++) {
        int f = n0 + wn + j * 16 + fm;
        float bias = b1[e * F_ + f];
        #pragma unroll
        for (int i = 0; i < 4; i++) {
            #pragma unroll
            for (int r = 0; r < 4; r++) {
                int m = m0 + wm + i * 16 + rbase + r;
                if (m < cnt) {
                    float v = acc[i][j][r] + bias;
                    v = v * normcdff(v);              // exact gelu: x * Phi(x)
                    h[(size_t)(off + m) * F_ + f] = f2bf(v);
                }
            }
        }
    }
}

// ---------------- GEMM2: y = (h @ W2[e] + b2[e]) * assign_weight ----------------
__global__ __launch_bounds__(256) void k_gemm2(
    const u16* __restrict__ h, const u16* __restrict__ w2t,
    const float* __restrict__ b2,
    const int* __restrict__ counts, const int* __restrict__ offsets,
    const float* __restrict__ assign_weight, float* __restrict__ y)
{
    int e = blockIdx.x >> 6;
    int mt = blockIdx.x & 63;
    int cnt = counts[e];
    int m0 = mt * 128;
    if (m0 >= cnt) return;
    int off = offsets[e];
    int n0 = blockIdx.y * 128;

    __shared__ __align__(16) u16 As[128 * 32];
    __shared__ __align__(16) u16 Bs[128 * 32];

    int tid = threadIdx.x;
    int w = tid >> 6, lane = tid & 63;
    int rA = lane >> 2;
    int colk = (lane & 3) * 8;
    int r0 = (w * 2 + 0) * 16 + rA;
    int r1 = (w * 2 + 1) * 16 + rA;

    // rows beyond cnt over-read into the y region of ws (harmless, masked at store)
    const u16* agp0 = h + (size_t)(off + m0 + r0) * F_ + colk;
    const u16* agp1 = h + (size_t)(off + m0 + r1) * F_ + colk;
    const u16* bgp0 = w2t + ((size_t)e * D_ + n0 + r0) * F_ + colk;
    const u16* bgp1 = w2t + ((size_t)e * D_ + n0 + r1) * F_ + colk;
    u16* al0 = &As[(w * 2 + 0) * 512 + lane * 8];
    u16* al1 = &As[(w * 2 + 1) * 512 + lane * 8];
    u16* bl0 = &Bs[(w * 2 + 0) * 512 + lane * 8];
    u16* bl1 = &Bs[(w * 2 + 1) * 512 + lane * 8];

    f32x4 acc[4][4];
    #pragma unroll
    for (int i = 0; i < 4; i++)
        #pragma unroll
        for (int j = 0; j < 4; j++) acc[i][j] = (f32x4){0.f, 0.f, 0.f, 0.f};

    int wm = (w >> 1) * 64, wn = (w & 1) * 64;
    int fm = lane & 15, k8 = (lane >> 4) * 8;

    for (int kk = 0; kk < F_; kk += 32) {
        async16(agp0 + kk, al0);
        async16(agp1 + kk, al1);
        async16(bgp0 + kk, bl0);
        async16(bgp1 + kk, bl1);
        __syncthreads();
        bf16x8 af[4], bfr[4];
        #pragma unroll
        for (int i = 0; i < 4; i++)
            af[i] = *(const bf16x8*)&As[(wm + i * 16 + fm) * 32 + k8];
        #pragma unroll
        for (int j = 0; j < 4; j++)
            bfr[j] = *(const bf16x8*)&Bs[(wn + j * 16 + fm) * 32 + k8];
        #pragma unroll
        for (int i = 0; i < 4; i++)
            #pragma unroll
            for (int j = 0; j < 4; j++)
                acc[i][j] = __builtin_amdgcn_mfma_f32_16x16x32_bf16(af[i], bfr[j], acc[i][j], 0, 0, 0);
        __syncthreads();
    }

    int rbase = (lane >> 4) * 4;
    #pragma unroll
    for (int j = 0; j < 4; j++) {
        int d = n0 + wn + j * 16 + fm;
        float bias = b2[e * D_ + d];
        #pragma unroll
        for (int i = 0; i < 4; i++) {
            #pragma unroll
            for (int r = 0; r < 4; r++) {
                int m = m0 + wm + i * 16 + rbase + r;
                if (m < cnt) {
                    float wgt = assign_weight[off + m];
                    y[(size_t)(off + m) * D_ + d] = (acc[i][j][r] + bias) * wgt;
                }
            }
        }
    }
}

// ---------------- combine: out[t] = y[pos0[t]] + y[pos1[t]] ----------------
__global__ void k_combine(const float* __restrict__ y, const int* __restrict__ pos,
                          float* __restrict__ out)
{
    int g = blockIdx.x * 256 + threadIdx.x;    // NTOK*192 threads (float4 per thread)
    int t = g / 192, c = g - t * 192;
    int p0 = pos[t * 2], p1 = pos[t * 2 + 1];
    const float4* y4 = (const float4*)y;
    float4 a = y4[(size_t)p0 * 192 + c];
    float4 b = y4[(size_t)p1 * 192 + c];
    float4 o = {a.x + b.x, a.y + b.y, a.z + b.z, a.w + b.w};
    ((float4*)out)[g] = o;
}

extern "C" void kernel_launch(void* const* d_in, const int* in_sizes, int n_in,
                              void* d_out, int out_size, void* d_ws, size_t ws_size,
                              hipStream_t stream)
{
    const float* x  = (const float*)d_in[0];
    const float* Wr = (const float*)d_in[1];
    const float* W1 = (const float*)d_in[2];
    const float* b1 = (const float*)d_in[3];
    const float* W2 = (const float*)d_in[4];
    const float* b2 = (const float*)d_in[5];
    float* out = (float*)d_out;

    char* base = (char*)d_ws;
    size_t o = 0;
    auto alloc = [&](size_t bytes) {
        char* r = base + o;
        o += (bytes + 255) & ~(size_t)255;
        return r;
    };
    int*   counts        = (int*)  alloc(E_ * 4);
    int*   cursors       = (int*)  alloc(E_ * 4);
    int*   offsets       = (int*)  alloc(E_ * 4);
    float* usage         = (float*)alloc(E_ * 4);
    float* zsum          = (float*)alloc(4);
    int*   tk_idx        = (int*)  alloc((size_t)NTOK * 2 * 4);
    float* tk_w          = (float*)alloc((size_t)NTOK * 2 * 4);
    int*   pos           = (int*)  alloc((size_t)NTOK * 2 * 4);
    int*   assign_token  = (int*)  alloc((size_t)NASSIGN * 4);
    float* assign_weight = (float*)alloc((size_t)NASSIGN * 4);
    u16*   xb            = (u16*)  alloc((size_t)NTOK * D_ * 2);
    u16*   w1t           = (u16*)  alloc((size_t)E_ * F_ * D_ * 2);
    u16*   w2t           = (u16*)  alloc((size_t)E_ * D_ * F_ * 2);
    u16*   hbuf          = (u16*)  alloc((size_t)NASSIGN * F_ * 2);
    float* y             = (float*)alloc((size_t)NASSIGN * D_ * 4);  // keep after hbuf (over-read guard)

    k_init<<<dim3(1), dim3(64), 0, stream>>>(usage, zsum, counts, cursors);
    k_cvt_x<<<dim3(NTOK * D_ / 1024), dim3(256), 0, stream>>>(x, xb);
    k_tcvt<<<dim3(F_ / 32, D_ / 32, E_), dim3(256), 0, stream>>>(W1, w1t, D_, F_);
    k_tcvt<<<dim3(D_ / 32, F_ / 32, E_), dim3(256), 0, stream>>>(W2, w2t, F_, D_);
    k_router<<<dim3(NTOK / 4), dim3(256), 0, stream>>>(x, Wr, usage, zsum, counts, tk_idx, tk_w);
    k_scan_finalize<<<dim3(1), dim3(64), 0, stream>>>(counts, offsets, usage, zsum, out + (size_t)NTOK * D_);
    k_fill<<<dim3(NTOK / 256), dim3(256), 0, stream>>>(tk_idx, tk_w, offsets, cursors, assign_token, assign_weight, pos);
    k_gemm1<<<dim3(E_ * 64, F_ / 128), dim3(256), 0, stream>>>(xb, w1t, b1, counts, offsets, assign_token, hbuf);
    k_gemm2<<<dim3(E_ * 64, D_ / 128), dim3(256), 0, stream>>>(hbuf, w2t, b2, counts, offsets, assign_weight, y);
    k_combine<<<dim3(NTOK * D_ / 1024), dim3(256), 0, stream>>>(y, pos, out);
}

// Round 2
// 864.606 us; speedup vs baseline: 1.9889x; 1.9889x over previous
//
#include <hip/hip_runtime.h>
#include <cstdint>
#include <cstddef>

#define B_ 4
#define S_ 2048
#define D_ 768
#define F_ 3072
#define E_ 8
#define NTOK (B_*S_)        // 8192
#define NASSIGN (NTOK*2)    // 16384 (every token has exactly 2 experts)
#define RBLK 256            // router blocks (32 tokens each)
#define FBLK 32             // fill blocks (256 tokens each)

typedef unsigned short u16;
typedef __attribute__((ext_vector_type(8))) __bf16 bf16x8;
typedef __attribute__((ext_vector_type(4))) float f32x4;

__device__ __forceinline__ u16 f2bf(float f) {
    unsigned int u = __builtin_bit_cast(unsigned int, f);
    u += 0x7fffu + ((u >> 16) & 1u);   // RNE
    return (u16)(u >> 16);
}

__device__ __forceinline__ void async16(const void* g, void* l) {
    __builtin_amdgcn_global_load_lds(
        (const __attribute__((address_space(1))) unsigned int*)g,
        (__attribute__((address_space(3))) unsigned int*)l, 16, 0, 0);
}

// ---------------- init (zero cursors only; no global accumulators anymore) ----------------
__global__ void k_init(int* cursors) {
    int t = threadIdx.x;
    if (t < E_) cursors[t] = 0;
}

// ---------------- x fp32 -> bf16 ----------------
__global__ void k_cvt_x(const float* __restrict__ x, u16* __restrict__ xb) {
    int id = blockIdx.x * 256 + threadIdx.x;     // NTOK*D_/4 threads
    float4 v = ((const float4*)x)[id];
    ushort4 o;
    o.x = f2bf(v.x); o.y = f2bf(v.y); o.z = f2bf(v.z); o.w = f2bf(v.w);
    ((ushort4*)xb)[id] = o;
}

// ------------- weight transpose+convert: in[e][R][C] f32 -> out[e][C][R] bf16 -------------
__global__ void k_tcvt(const float* __restrict__ in, u16* __restrict__ out, int R, int C) {
    __shared__ u16 t[32][33];
    int e = blockIdx.z;
    int c0 = blockIdx.x * 32, r0 = blockIdx.y * 32;
    int tx = threadIdx.x & 31, ty = threadIdx.x >> 5;    // 32x8
    const float* ip = in + (size_t)e * R * C;
    u16* op = out + (size_t)e * C * R;
    #pragma unroll
    for (int i = 0; i < 32; i += 8)
        t[ty + i][tx] = f2bf(ip[(size_t)(r0 + ty + i) * C + (c0 + tx)]);
    __syncthreads();
    #pragma unroll
    for (int i = 0; i < 32; i += 8)
        op[(size_t)(c0 + ty + i) * R + (r0 + tx)] = t[tx][ty + i];
}

// ---------------- router: logits, softmax, top-2; per-block partials, NO global atomics ----------------
__global__ __launch_bounds__(256) void k_router(
    const float* __restrict__ x, const float* __restrict__ Wr,
    float* __restrict__ usage_part,   // [RBLK][E_]
    float* __restrict__ z_part,       // [RBLK]
    int*   __restrict__ hist_part,    // [RBLK][E_]
    int* __restrict__ tk_idx, float* __restrict__ tk_w)
{
    __shared__ float wrt[E_ * D_];    // Wr transposed: [e][d]
    __shared__ float s_usage[E_];
    __shared__ float s_z;
    __shared__ int   s_hist[E_];
    int tid = threadIdx.x;
    for (int i = tid; i < E_ * D_; i += 256) {
        int d = i >> 3, e = i & 7;
        wrt[e * D_ + d] = Wr[i];
    }
    if (tid < E_) { s_usage[tid] = 0.f; s_hist[tid] = 0; }
    if (tid == 0) s_z = 0.f;
    __syncthreads();

    int w = tid >> 6, lane = tid & 63;
    float u_acc[E_];
    #pragma unroll
    for (int e = 0; e < E_; e++) u_acc[e] = 0.f;
    float z_acc = 0.f;

    for (int it = 0; it < 8; it++) {
        int tok = blockIdx.x * 32 + it * 4 + w;   // one wave per token
        float acc[E_];
        #pragma unroll
        for (int e = 0; e < E_; e++) acc[e] = 0.f;
        const float* xr = x + (size_t)tok * D_;
        for (int d = lane; d < D_; d += 64) {
            float xv = xr[d];
            #pragma unroll
            for (int e = 0; e < E_; e++) acc[e] += xv * wrt[e * D_ + d];
        }
        #pragma unroll
        for (int off = 32; off > 0; off >>= 1) {
            #pragma unroll
            for (int e = 0; e < E_; e++) acc[e] += __shfl_down(acc[e], off);
        }
        if (lane == 0) {
            float m = acc[0];
            #pragma unroll
            for (int e = 1; e < E_; e++) m = fmaxf(m, acc[e]);
            float p[E_], s = 0.f;
            #pragma unroll
            for (int e = 0; e < E_; e++) { p[e] = expf(acc[e] - m); s += p[e]; }
            float inv = 1.f / s;
            #pragma unroll
            for (int e = 0; e < E_; e++) { p[e] *= inv; u_acc[e] += p[e]; }
            float lse = m + logf(s);
            z_acc += lse * lse;
            // top-2 (earliest index wins ties, matching lax.top_k)
            int i1 = 0;
            for (int e = 1; e < E_; e++) if (p[e] > p[i1]) i1 = e;
            int i2 = -1;
            for (int e = 0; e < E_; e++) {
                if (e == i1) continue;
                if (i2 < 0 || p[e] > p[i2]) i2 = e;
            }
            float denom = p[i1] + p[i2] + 1e-8f;
            tk_idx[tok * 2 + 0] = i1; tk_idx[tok * 2 + 1] = i2;
            tk_w[tok * 2 + 0] = p[i1] / denom;
            tk_w[tok * 2 + 1] = p[i2] / denom;
            atomicAdd(&s_hist[i1], 1); atomicAdd(&s_hist[i2], 1);   // LDS atomics, cheap
        }
    }
    if (lane == 0) {
        #pragma unroll
        for (int e = 0; e < E_; e++) atomicAdd(&s_usage[e], u_acc[e]);  // LDS
        atomicAdd(&s_z, z_acc);                                         // LDS
    }
    __syncthreads();
    if (tid < E_) {
        usage_part[blockIdx.x * E_ + tid] = s_usage[tid];
        hist_part[blockIdx.x * E_ + tid]  = s_hist[tid];
    }
    if (tid == 0) z_part[blockIdx.x] = s_z;
}

// ---------------- reduce partials -> counts/offsets + scalar losses ----------------
__global__ __launch_bounds__(256) void k_finalize(
    const float* __restrict__ usage_part, const float* __restrict__ z_part,
    const int* __restrict__ hist_part,
    int* __restrict__ counts, int* __restrict__ offsets,
    float* __restrict__ out_scalars)
{
    __shared__ float s_u[E_];
    __shared__ float s_z;
    __shared__ int   s_h[E_];
    int tid = threadIdx.x;
    if (tid < E_) { s_u[tid] = 0.f; s_h[tid] = 0; }
    if (tid == 0) s_z = 0.f;
    __syncthreads();

    float u[E_]; int h[E_];
    #pragma unroll
    for (int e = 0; e < E_; e++) { u[e] = usage_part[tid * E_ + e]; h[e] = hist_part[tid * E_ + e]; }
    float z = z_part[tid];
    #pragma unroll
    for (int off = 32; off > 0; off >>= 1) {
        #pragma unroll
        for (int e = 0; e < E_; e++) {
            u[e] += __shfl_down(u[e], off);
            h[e] += __shfl_down(h[e], off);
        }
        z += __shfl_down(z, off);
    }
    if ((tid & 63) == 0) {
        #pragma unroll
        for (int e = 0; e < E_; e++) { atomicAdd(&s_u[e], u[e]); atomicAdd(&s_h[e], h[e]); }
        atomicAdd(&s_z, z);
    }
    __syncthreads();
    if (tid == 0) {
        int o = 0;
        for (int e = 0; e < E_; e++) { counts[e] = s_h[e]; offsets[e] = o; o += s_h[e]; }
        float uu[E_], mean = 0.f;
        for (int e = 0; e < E_; e++) { uu[e] = s_u[e] / (float)NTOK; mean += uu[e]; }
        mean /= (float)E_;
        float var = 0.f;
        for (int e = 0; e < E_; e++) { float d = uu[e] - mean; var += d * d; }
        var /= (float)E_;
        out_scalars[0] = var / (mean * mean + 1e-8f) * (float)E_ * 0.01f;  // lb_loss
        out_scalars[1] = (s_z / (float)NTOK) * 0.001f;                      // z_loss
    }
}

// ---------------- build compact per-expert assignment lists (block-local ranks) ----------------
__global__ __launch_bounds__(256) void k_fill(
    const int* __restrict__ tk_idx, const float* __restrict__ tk_w,
    const int* __restrict__ offsets, int* __restrict__ cursors,
    int* __restrict__ assign_token, float* __restrict__ assign_weight,
    int* __restrict__ pos)
{
    __shared__ int l_cnt[E_];
    __shared__ int l_base[E_];
    int tid = threadIdx.x;
    if (tid < E_) l_cnt[tid] = 0;
    __syncthreads();
    int t = blockIdx.x * 256 + tid;
    int e0 = tk_idx[t * 2 + 0], e1 = tk_idx[t * 2 + 1];
    int r0 = atomicAdd(&l_cnt[e0], 1);            // LDS atomics
    int r1 = atomicAdd(&l_cnt[e1], 1);
    __syncthreads();
    if (tid < E_) l_base[tid] = atomicAdd(&cursors[tid], l_cnt[tid]);  // 8 global atomics/block
    __syncthreads();
    int row0 = offsets[e0] + l_base[e0] + r0;
    int row1 = offsets[e1] + l_base[e1] + r1;
    assign_token[row0] = t; assign_weight[row0] = tk_w[t * 2 + 0]; pos[t * 2 + 0] = row0;
    assign_token[row1] = t; assign_weight[row1] = tk_w[t * 2 + 1]; pos[t * 2 + 1] = row1;
}

// ---------------- GEMM1: h = gelu(gather(x) @ W1[e] + b1[e]), bf16 MFMA ----------------
__global__ __launch_bounds__(256) void k_gemm1(
    const u16* __restrict__ xb, const u16* __restrict__ w1t,
    const float* __restrict__ b1,
    const int* __restrict__ counts, const int* __restrict__ offsets,
    const int* __restrict__ assign_token, u16* __restrict__ h)
{
    int e = blockIdx.x >> 6;
    int mt = blockIdx.x & 63;
    int cnt = counts[e];
    int m0 = mt * 128;
    if (m0 >= cnt) return;
    int off = offsets[e];
    int n0 = blockIdx.y * 128;

    __shared__ __align__(16) u16 As[128 * 32];   // [m][k] K-major
    __shared__ __align__(16) u16 Bs[128 * 32];   // [n][k] K-major

    int tid = threadIdx.x;
    int w = tid >> 6, lane = tid & 63;
    int rA = lane >> 2;                 // row within 16-row chunk
    int colk = (lane & 3) * 8;          // k element offset within 32
    int r0 = (w * 2 + 0) * 16 + rA;
    int r1 = (w * 2 + 1) * 16 + rA;

    int g0 = m0 + r0; if (g0 > cnt - 1) g0 = cnt - 1;
    int g1 = m0 + r1; if (g1 > cnt - 1) g1 = cnt - 1;
    const u16* agp0 = xb + (size_t)assign_token[off + g0] * D_ + colk;
    const u16* agp1 = xb + (size_t)assign_token[off + g1] * D_ + colk;
    const u16* bgp0 = w1t + ((size_t)e * F_ + n0 + r0) * D_ + colk;
    const u16* bgp1 = w1t + ((size_t)e * F_ + n0 + r1) * D_ + colk;
    u16* al0 = &As[(w * 2 + 0) * 512 + lane * 8];
    u16* al1 = &As[(w * 2 + 1) * 512 + lane * 8];
    u16* bl0 = &Bs[(w * 2 + 0) * 512 + lane * 8];
    u16* bl1 = &Bs[(w * 2 + 1) * 512 + lane * 8];

    f32x4 acc[4][4];
    #pragma unroll
    for (int i = 0; i < 4; i++)
        #pragma unroll
        for (int j = 0; j < 4; j++) acc[i][j] = (f32x4){0.f, 0.f, 0.f, 0.f};

    int wm = (w >> 1) * 64, wn = (w & 1) * 64;
    int fm = lane & 15, k8 = (lane >> 4) * 8;

    for (int kk = 0; kk < D_; kk += 32) {
        async16(agp0 + kk, al0);
        async16(agp1 + kk, al1);
        async16(bgp0 + kk, bl0);
        async16(bgp1 + kk, bl1);
        __syncthreads();
        bf16x8 af[4], bfr[4];
        #pragma unroll
        for (int i = 0; i < 4; i++)
            af[i] = *(const bf16x8*)&As[(wm + i * 16 + fm) * 32 + k8];
        #pragma unroll
        for (int j = 0; j < 4; j++)
            bfr[j] = *(const bf16x8*)&Bs[(wn + j * 16 + fm) * 32 + k8];
        #pragma unroll
        for (int i = 0; i < 4; i++)
            #pragma unroll
            for (int j = 0; j < 4; j++)
                acc[i][j] = __builtin_amdgcn_mfma_f32_16x16x32_bf16(af[i], bfr[j], acc[i][j], 0, 0, 0);
        __syncthreads();
    }

    int rbase = (lane >> 4) * 4;
    #pragma unroll
    for (int j = 0; j < 4; j++) {
        int f = n0 + wn + j * 16 + fm;
        float bias = b1[e * F_ + f];
        #pragma unroll
        for (int i = 0; i < 4; i++) {
            #pragma unroll
            for (int r = 0; r < 4; r++) {
                int m = m0 + wm + i * 16 + rbase + r;
                if (m < cnt) {
                    float v = acc[i][j][r] + bias;
                    v = v * normcdff(v);              // exact gelu: x * Phi(x)
                    h[(size_t)(off + m) * F_ + f] = f2bf(v);
                }
            }
        }
    }
}

// ---------------- GEMM2: y = (h @ W2[e] + b2[e]) * assign_weight ----------------
__global__ __launch_bounds__(256) void k_gemm2(
    const u16* __restrict__ h, const u16* __restrict__ w2t,
    const float* __restrict__ b2,
    const int* __restrict__ counts, const int* __restrict__ offsets,
    const float* __restrict__ assign_weight, float* __restrict__ y)
{
    int e = blockIdx.x >> 6;
    int mt = blockIdx.x & 63;
    int cnt = counts[e];
    int m0 = mt * 128;
    if (m0 >= cnt) return;
    int off = offsets[e];
    int n0 = blockIdx.y * 128;

    __shared__ __align__(16) u16 As[128 * 32];
    __shared__ __align__(16) u16 Bs[128 * 32];

    int tid = threadIdx.x;
    int w = tid >> 6, lane = tid & 63;
    int rA = lane >> 2;
    int colk = (lane & 3) * 8;
    int r0 = (w * 2 + 0) * 16 + rA;
    int r1 = (w * 2 + 1) * 16 + rA;

    // rows beyond cnt over-read into the y region of ws (harmless, masked at store)
    const u16* agp0 = h + (size_t)(off + m0 + r0) * F_ + colk;
    const u16* agp1 = h + (size_t)(off + m0 + r1) * F_ + colk;
    const u16* bgp0 = w2t + ((size_t)e * D_ + n0 + r0) * F_ + colk;
    const u16* bgp1 = w2t + ((size_t)e * D_ + n0 + r1) * F_ + colk;
    u16* al0 = &As[(w * 2 + 0) * 512 + lane * 8];
    u16* al1 = &As[(w * 2 + 1) * 512 + lane * 8];
    u16* bl0 = &Bs[(w * 2 + 0) * 512 + lane * 8];
    u16* bl1 = &Bs[(w * 2 + 1) * 512 + lane * 8];

    f32x4 acc[4][4];
    #pragma unroll
    for (int i = 0; i < 4; i++)
        #pragma unroll
        for (int j = 0; j < 4; j++) acc[i][j] = (f32x4){0.f, 0.f, 0.f, 0.f};

    int wm = (w >> 1) * 64, wn = (w & 1) * 64;
    int fm = lane & 15, k8 = (lane >> 4) * 8;

    for (int kk = 0; kk < F_; kk += 32) {
        async16(agp0 + kk, al0);
        async16(agp1 + kk, al1);
        async16(bgp0 + kk, bl0);
        async16(bgp1 + kk, bl1);
        __syncthreads();
        bf16x8 af[4], bfr[4];
        #pragma unroll
        for (int i = 0; i < 4; i++)
            af[i] = *(const bf16x8*)&As[(wm + i * 16 + fm) * 32 + k8];
        #pragma unroll
        for (int j = 0; j < 4; j++)
            bfr[j] = *(const bf16x8*)&Bs[(wn + j * 16 + fm) * 32 + k8];
        #pragma unroll
        for (int i = 0; i < 4; i++)
            #pragma unroll
            for (int j = 0; j < 4; j++)
                acc[i][j] = __builtin_amdgcn_mfma_f32_16x16x32_bf16(af[i], bfr[j], acc[i][j], 0, 0, 0);
        __syncthreads();
    }

    int rbase = (lane >> 4) * 4;
    #pragma unroll
    for (int j = 0; j < 4; j++) {
        int d = n0 + wn + j * 16 + fm;
        float bias = b2[e * D_ + d];
        #pragma unroll
        for (int i = 0; i < 4; i++) {
            #pragma unroll
            for (int r = 0; r < 4; r++) {
                int m = m0 + wm + i * 16 + rbase + r;
                if (m < cnt) {
                    float wgt = assign_weight[off + m];
                    y[(size_t)(off + m) * D_ + d] = (acc[i][j][r] + bias) * wgt;
                }
            }
        }
    }
}

// ---------------- combine: out[t] = y[pos0[t]] + y[pos1[t]] ----------------
__global__ void k_combine(const float* __restrict__ y, const int* __restrict__ pos,
                          float* __restrict__ out)
{
    int g = blockIdx.x * 256 + threadIdx.x;    // NTOK*192 threads (float4 per thread)
    int t = g / 192, c = g - t * 192;
    int p0 = pos[t * 2], p1 = pos[t * 2 + 1];
    const float4* y4 = (const float4*)y;
    float4 a = y4[(size_t)p0 * 192 + c];
    float4 b = y4[(size_t)p1 * 192 + c];
    float4 o = {a.x + b.x, a.y + b.y, a.z + b.z, a.w + b.w};
    ((float4*)out)[g] = o;
}

extern "C" void kernel_launch(void* const* d_in, const int* in_sizes, int n_in,
                              void* d_out, int out_size, void* d_ws, size_t ws_size,
                              hipStream_t stream)
{
    const float* x  = (const float*)d_in[0];
    const float* Wr = (const float*)d_in[1];
    const float* W1 = (const float*)d_in[2];
    const float* b1 = (const float*)d_in[3];
    const float* W2 = (const float*)d_in[4];
    const float* b2 = (const float*)d_in[5];
    float* out = (float*)d_out;

    char* base = (char*)d_ws;
    size_t o = 0;
    auto alloc = [&](size_t bytes) {
        char* r = base + o;
        o += (bytes + 255) & ~(size_t)255;
        return r;
    };
    int*   counts        = (int*)  alloc(E_ * 4);
    int*   cursors       = (int*)  alloc(E_ * 4);
    int*   offsets       = (int*)  alloc(E_ * 4);
    float* usage_part    = (float*)alloc((size_t)RBLK * E_ * 4);
    float* z_part        = (float*)alloc((size_t)RBLK * 4);
    int*   hist_part     = (int*)  alloc((size_t)RBLK * E_ * 4);
    int*   tk_idx        = (int*)  alloc((size_t)NTOK * 2 * 4);
    float* tk_w          = (float*)alloc((size_t)NTOK * 2 * 4);
    int*   pos           = (int*)  alloc((size_t)NTOK * 2 * 4);
    int*   assign_token  = (int*)  alloc((size_t)NASSIGN * 4);
    float* assign_weight = (float*)alloc((size_t)NASSIGN * 4);
    u16*   xb            = (u16*)  alloc((size_t)NTOK * D_ * 2);
    u16*   w1t           = (u16*)  alloc((size_t)E_ * F_ * D_ * 2);
    u16*   w2t           = (u16*)  alloc((size_t)E_ * D_ * F_ * 2);
    u16*   hbuf          = (u16*)  alloc((size_t)NASSIGN * F_ * 2);
    float* y             = (float*)alloc((size_t)NASSIGN * D_ * 4);  // keep after hbuf (over-read guard)

    k_init<<<dim3(1), dim3(64), 0, stream>>>(cursors);
    k_cvt_x<<<dim3(NTOK * D_ / 1024), dim3(256), 0, stream>>>(x, xb);
    k_tcvt<<<dim3(F_ / 32, D_ / 32, E_), dim3(256), 0, stream>>>(W1, w1t, D_, F_);
    k_tcvt<<<dim3(D_ / 32, F_ / 32, E_), dim3(256), 0, stream>>>(W2, w2t, F_, D_);
    k_router<<<dim3(RBLK), dim3(256), 0, stream>>>(x, Wr, usage_part, z_part, hist_part, tk_idx, tk_w);
    k_finalize<<<dim3(1), dim3(256), 0, stream>>>(usage_part, z_part, hist_part, counts, offsets,
                                                  out + (size_t)NTOK * D_);
    k_fill<<<dim3(FBLK), dim3(256), 0, stream>>>(tk_idx, tk_w, offsets, cursors, assign_token, assign_weight, pos);
    k_gemm1<<<dim3(E_ * 64, F_ / 128), dim3(256), 0, stream>>>(xb, w1t, b1, counts, offsets, assign_token, hbuf);
    k_gemm2<<<dim3(E_ * 64, D_ / 128), dim3(256), 0, stream>>>(hbuf, w2t, b2, counts, offsets, assign_weight, y);
    k_combine<<<dim3(NTOK * D_ / 1024), dim3(256), 0, stream>>>(y, pos, out);
}

// Round 3
// 763.270 us; speedup vs baseline: 2.2529x; 1.1328x over previous
//
#include <hip/hip_runtime.h>
#include <cstdint>
#include <cstddef>

#define B_ 4
#define S_ 2048
#define D_ 768
#define F_ 3072
#define E_ 8
#define NTOK (B_*S_)        // 8192
#define NASSIGN (NTOK*2)    // 16384 (every token has exactly 2 experts)
#define RBLK 256            // router blocks (32 tokens each)
#define FBLK 32             // fill blocks (256 tokens each)

typedef unsigned short u16;
typedef __attribute__((ext_vector_type(8))) __bf16 bf16x8;
typedef __attribute__((ext_vector_type(4))) float f32x4;

__device__ __forceinline__ u16 f2bf(float f) {
    unsigned int u = __builtin_bit_cast(unsigned int, f);
    u += 0x7fffu + ((u >> 16) & 1u);   // RNE
    return (u16)(u >> 16);
}

// global->LDS async copy, 16B/lane. lds base MUST be wave-uniform:
// HW writes lane i at lds + 16*i (m104/m108). Callers pass a scalarized base.
__device__ __forceinline__ void async16(const void* g, void* l) {
    __builtin_amdgcn_global_load_lds(
        (const __attribute__((address_space(1))) unsigned int*)g,
        (__attribute__((address_space(3))) unsigned int*)l, 16, 0, 0);
}

// exact-gelu x*Phi(x) via A&S 7.1.26 erf (|err|<=1.5e-7), branch-free, ~15 VALU ops
__device__ __forceinline__ float gelu_f(float v) {
    float z = v * 0.70710678f;
    float a = fabsf(z);
    float t = __builtin_amdgcn_rcpf(1.0f + 0.3275911f * a);
    float poly = t * (0.254829592f + t * (-0.284496736f + t * (1.421413741f +
                 t * (-1.453152027f + t * 1.061405429f))));
    float e = __expf(-z * z);
    float erf_a = 1.0f - poly * e;
    float erf_z = copysignf(erf_a, z);
    return 0.5f * v * (1.0f + erf_z);
}

// ---------------- init (zero cursors only) ----------------
__global__ void k_init(int* cursors) {
    int t = threadIdx.x;
    if (t < E_) cursors[t] = 0;
}

// ---------------- x fp32 -> bf16 ----------------
__global__ void k_cvt_x(const float* __restrict__ x, u16* __restrict__ xb) {
    int id = blockIdx.x * 256 + threadIdx.x;     // NTOK*D_/4 threads
    float4 v = ((const float4*)x)[id];
    ushort4 o;
    o.x = f2bf(v.x); o.y = f2bf(v.y); o.z = f2bf(v.z); o.w = f2bf(v.w);
    ((ushort4*)xb)[id] = o;
}

// ------------- weight transpose+convert: in[e][R][C] f32 -> out[e][C][R] bf16 -------------
__global__ void k_tcvt(const float* __restrict__ in, u16* __restrict__ out, int R, int C) {
    __shared__ u16 t[32][33];
    int e = blockIdx.z;
    int c0 = blockIdx.x * 32, r0 = blockIdx.y * 32;
    int tx = threadIdx.x & 31, ty = threadIdx.x >> 5;    // 32x8
    const float* ip = in + (size_t)e * R * C;
    u16* op = out + (size_t)e * C * R;
    #pragma unroll
    for (int i = 0; i < 32; i += 8)
        t[ty + i][tx] = f2bf(ip[(size_t)(r0 + ty + i) * C + (c0 + tx)]);
    __syncthreads();
    #pragma unroll
    for (int i = 0; i < 32; i += 8)
        op[(size_t)(c0 + ty + i) * R + (r0 + tx)] = t[tx][ty + i];
}

// ---------------- router: logits, softmax, top-2; per-block partials, NO global atomics ----------------
__global__ __launch_bounds__(256) void k_router(
    const float* __restrict__ x, const float* __restrict__ Wr,
    float* __restrict__ usage_part,   // [RBLK][E_]
    float* __restrict__ z_part,       // [RBLK]
    int*   __restrict__ hist_part,    // [RBLK][E_]
    int* __restrict__ tk_idx, float* __restrict__ tk_w)
{
    __shared__ float wrt[E_ * D_];    // Wr transposed: [e][d]
    __shared__ float s_usage[E_];
    __shared__ float s_z;
    __shared__ int   s_hist[E_];
    int tid = threadIdx.x;
    for (int i = tid; i < E_ * D_; i += 256) {
        int d = i >> 3, e = i & 7;
        wrt[e * D_ + d] = Wr[i];
    }
    if (tid < E_) { s_usage[tid] = 0.f; s_hist[tid] = 0; }
    if (tid == 0) s_z = 0.f;
    __syncthreads();

    int w = tid >> 6, lane = tid & 63;
    float u_acc[E_];
    #pragma unroll
    for (int e = 0; e < E_; e++) u_acc[e] = 0.f;
    float z_acc = 0.f;

    for (int it = 0; it < 8; it++) {
        int tok = blockIdx.x * 32 + it * 4 + w;   // one wave per token
        float acc[E_];
        #pragma unroll
        for (int e = 0; e < E_; e++) acc[e] = 0.f;
        const float* xr = x + (size_t)tok * D_;
        for (int d = lane; d < D_; d += 64) {
            float xv = xr[d];
            #pragma unroll
            for (int e = 0; e < E_; e++) acc[e] += xv * wrt[e * D_ + d];
        }
        #pragma unroll
        for (int off = 32; off > 0; off >>= 1) {
            #pragma unroll
            for (int e = 0; e < E_; e++) acc[e] += __shfl_down(acc[e], off);
        }
        if (lane == 0) {
            float m = acc[0];
            #pragma unroll
            for (int e = 1; e < E_; e++) m = fmaxf(m, acc[e]);
            float p[E_], s = 0.f;
            #pragma unroll
            for (int e = 0; e < E_; e++) { p[e] = expf(acc[e] - m); s += p[e]; }
            float inv = 1.f / s;
            #pragma unroll
            for (int e = 0; e < E_; e++) { p[e] *= inv; u_acc[e] += p[e]; }
            float lse = m + logf(s);
            z_acc += lse * lse;
            // top-2 (earliest index wins ties, matching lax.top_k)
            int i1 = 0;
            for (int e = 1; e < E_; e++) if (p[e] > p[i1]) i1 = e;
            int i2 = -1;
            for (int e = 0; e < E_; e++) {
                if (e == i1) continue;
                if (i2 < 0 || p[e] > p[i2]) i2 = e;
            }
            float denom = p[i1] + p[i2] + 1e-8f;
            tk_idx[tok * 2 + 0] = i1; tk_idx[tok * 2 + 1] = i2;
            tk_w[tok * 2 + 0] = p[i1] / denom;
            tk_w[tok * 2 + 1] = p[i2] / denom;
            atomicAdd(&s_hist[i1], 1); atomicAdd(&s_hist[i2], 1);   // LDS atomics, cheap
        }
    }
    if (lane == 0) {
        #pragma unroll
        for (int e = 0; e < E_; e++) atomicAdd(&s_usage[e], u_acc[e]);  // LDS
        atomicAdd(&s_z, z_acc);                                         // LDS
    }
    __syncthreads();
    if (tid < E_) {
        usage_part[blockIdx.x * E_ + tid] = s_usage[tid];
        hist_part[blockIdx.x * E_ + tid]  = s_hist[tid];
    }
    if (tid == 0) z_part[blockIdx.x] = s_z;
}

// ---------------- reduce partials -> counts/offsets + scalar losses ----------------
__global__ __launch_bounds__(256) void k_finalize(
    const float* __restrict__ usage_part, const float* __restrict__ z_part,
    const int* __restrict__ hist_part,
    int* __restrict__ counts, int* __restrict__ offsets,
    float* __restrict__ out_scalars)
{
    __shared__ float s_u[E_];
    __shared__ float s_z;
    __shared__ int   s_h[E_];
    int tid = threadIdx.x;
    if (tid < E_) { s_u[tid] = 0.f; s_h[tid] = 0; }
    if (tid == 0) s_z = 0.f;
    __syncthreads();

    float u[E_]; int h[E_];
    #pragma unroll
    for (int e = 0; e < E_; e++) { u[e] = usage_part[tid * E_ + e]; h[e] = hist_part[tid * E_ + e]; }
    float z = z_part[tid];
    #pragma unroll
    for (int off = 32; off > 0; off >>= 1) {
        #pragma unroll
        for (int e = 0; e < E_; e++) {
            u[e] += __shfl_down(u[e], off);
            h[e] += __shfl_down(h[e], off);
        }
        z += __shfl_down(z, off);
    }
    if ((tid & 63) == 0) {
        #pragma unroll
        for (int e = 0; e < E_; e++) { atomicAdd(&s_u[e], u[e]); atomicAdd(&s_h[e], h[e]); }
        atomicAdd(&s_z, z);
    }
    __syncthreads();
    if (tid == 0) {
        int o = 0;
        for (int e = 0; e < E_; e++) { counts[e] = s_h[e]; offsets[e] = o; o += s_h[e]; }
        float uu[E_], mean = 0.f;
        for (int e = 0; e < E_; e++) { uu[e] = s_u[e] / (float)NTOK; mean += uu[e]; }
        mean /= (float)E_;
        float var = 0.f;
        for (int e = 0; e < E_; e++) { float d = uu[e] - mean; var += d * d; }
        var /= (float)E_;
        out_scalars[0] = var / (mean * mean + 1e-8f) * (float)E_ * 0.01f;  // lb_loss
        out_scalars[1] = (s_z / (float)NTOK) * 0.001f;                      // z_loss
    }
}

// ---------------- build compact per-expert assignment lists (block-local ranks) ----------------
__global__ __launch_bounds__(256) void k_fill(
    const int* __restrict__ tk_idx, const float* __restrict__ tk_w,
    const int* __restrict__ offsets, int* __restrict__ cursors,
    int* __restrict__ assign_token, float* __restrict__ assign_weight,
    int* __restrict__ pos)
{
    __shared__ int l_cnt[E_];
    __shared__ int l_base[E_];
    int tid = threadIdx.x;
    if (tid < E_) l_cnt[tid] = 0;
    __syncthreads();
    int t = blockIdx.x * 256 + tid;
    int e0 = tk_idx[t * 2 + 0], e1 = tk_idx[t * 2 + 1];
    int r0 = atomicAdd(&l_cnt[e0], 1);            // LDS atomics
    int r1 = atomicAdd(&l_cnt[e1], 1);
    __syncthreads();
    if (tid < E_) l_base[tid] = atomicAdd(&cursors[tid], l_cnt[tid]);  // 8 global atomics/block
    __syncthreads();
    int row0 = offsets[e0] + l_base[e0] + r0;
    int row1 = offsets[e1] + l_base[e1] + r1;
    assign_token[row0] = t; assign_weight[row0] = tk_w[t * 2 + 0]; pos[t * 2 + 0] = row0;
    assign_token[row1] = t; assign_weight[row1] = tk_w[t * 2 + 1]; pos[t * 2 + 1] = row1;
}

// ---------------- GEMM1: h = gelu(gather(x) @ W1[e] + b1[e]), bf16 MFMA ----------------
__global__ __launch_bounds__(256) void k_gemm1(
    const u16* __restrict__ xb, const u16* __restrict__ w1t,
    const float* __restrict__ b1,
    const int* __restrict__ counts, const int* __restrict__ offsets,
    const int* __restrict__ assign_token, u16* __restrict__ h)
{
    int e = blockIdx.x >> 6;
    int mt = blockIdx.x & 63;
    int cnt = counts[e];
    int m0 = mt * 128;
    if (m0 >= cnt) return;
    int off = offsets[e];
    int n0 = blockIdx.y * 128;

    __shared__ __align__(16) u16 As[128 * 32];   // [m][k] K-major, 8 chunks of 1KB
    __shared__ __align__(16) u16 Bs[128 * 32];

    int tid = threadIdx.x;
    int w = tid >> 6, lane = tid & 63;
    int rA = lane >> 2;                 // row within 16-row chunk
    int colk = (lane & 3) * 8;          // k element offset within 32
    int r0 = (w * 2 + 0) * 16 + rA;
    int r1 = (w * 2 + 1) * 16 + rA;

    // wave-uniform LDS chunk bases (HW scatters lane i at +16*i)
    int c0b = __builtin_amdgcn_readfirstlane((w * 2 + 0) * 1024);
    int c1b = __builtin_amdgcn_readfirstlane((w * 2 + 1) * 1024);
    u16* al0 = (u16*)((char*)As + c0b);
    u16* al1 = (u16*)((char*)As + c1b);
    u16* bl0 = (u16*)((char*)Bs + c0b);
    u16* bl1 = (u16*)((char*)Bs + c1b);

    int g0 = m0 + r0; if (g0 > cnt - 1) g0 = cnt - 1;
    int g1 = m0 + r1; if (g1 > cnt - 1) g1 = cnt - 1;
    const u16* agp0 = xb + (size_t)assign_token[off + g0] * D_ + colk;
    const u16* agp1 = xb + (size_t)assign_token[off + g1] * D_ + colk;
    const u16* bgp0 = w1t + ((size_t)e * F_ + n0 + r0) * D_ + colk;
    const u16* bgp1 = w1t + ((size_t)e * F_ + n0 + r1) * D_ + colk;

    f32x4 acc[4][4];
    #pragma unroll
    for (int i = 0; i < 4; i++)
        #pragma unroll
        for (int j = 0; j < 4; j++) acc[i][j] = (f32x4){0.f, 0.f, 0.f, 0.f};

    int wm = (w >> 1) * 64, wn = (w & 1) * 64;
    int fm = lane & 15, k8 = (lane >> 4) * 8;

    for (int kk = 0; kk < D_; kk += 32) {
        async16(agp0 + kk, al0);
        async16(agp1 + kk, al1);
        async16(bgp0 + kk, bl0);
        async16(bgp1 + kk, bl1);
        __syncthreads();
        bf16x8 af[4], bfr[4];
        #pragma unroll
        for (int i = 0; i < 4; i++)
            af[i] = *(const bf16x8*)&As[(wm + i * 16 + fm) * 32 + k8];
        #pragma unroll
        for (int j = 0; j < 4; j++)
            bfr[j] = *(const bf16x8*)&Bs[(wn + j * 16 + fm) * 32 + k8];
        #pragma unroll
        for (int i = 0; i < 4; i++)
            #pragma unroll
            for (int j = 0; j < 4; j++)
                acc[i][j] = __builtin_amdgcn_mfma_f32_16x16x32_bf16(af[i], bfr[j], acc[i][j], 0, 0, 0);
        __syncthreads();
    }

    int rbase = (lane >> 4) * 4;
    #pragma unroll
    for (int j = 0; j < 4; j++) {
        int f = n0 + wn + j * 16 + fm;
        float bias = b1[e * F_ + f];
        #pragma unroll
        for (int i = 0; i < 4; i++) {
            #pragma unroll
            for (int r = 0; r < 4; r++) {
                int m = m0 + wm + i * 16 + rbase + r;
                if (m < cnt) {
                    float v = acc[i][j][r] + bias;
                    h[(size_t)(off + m) * F_ + f] = f2bf(gelu_f(v));
                }
            }
        }
    }
}

// ---------------- GEMM2: y = (h @ W2[e] + b2[e]) * assign_weight ----------------
__global__ __launch_bounds__(256) void k_gemm2(
    const u16* __restrict__ h, const u16* __restrict__ w2t,
    const float* __restrict__ b2,
    const int* __restrict__ counts, const int* __restrict__ offsets,
    const float* __restrict__ assign_weight, float* __restrict__ y)
{
    int e = blockIdx.x >> 6;
    int mt = blockIdx.x & 63;
    int cnt = counts[e];
    int m0 = mt * 128;
    if (m0 >= cnt) return;
    int off = offsets[e];
    int n0 = blockIdx.y * 128;

    __shared__ __align__(16) u16 As[128 * 32];
    __shared__ __align__(16) u16 Bs[128 * 32];

    int tid = threadIdx.x;
    int w = tid >> 6, lane = tid & 63;
    int rA = lane >> 2;
    int colk = (lane & 3) * 8;
    int r0 = (w * 2 + 0) * 16 + rA;
    int r1 = (w * 2 + 1) * 16 + rA;

    int c0b = __builtin_amdgcn_readfirstlane((w * 2 + 0) * 1024);
    int c1b = __builtin_amdgcn_readfirstlane((w * 2 + 1) * 1024);
    u16* al0 = (u16*)((char*)As + c0b);
    u16* al1 = (u16*)((char*)As + c1b);
    u16* bl0 = (u16*)((char*)Bs + c0b);
    u16* bl1 = (u16*)((char*)Bs + c1b);

    // rows beyond cnt over-read into the y region of ws (harmless, masked at store)
    const u16* agp0 = h + (size_t)(off + m0 + r0) * F_ + colk;
    const u16* agp1 = h + (size_t)(off + m0 + r1) * F_ + colk;
    const u16* bgp0 = w2t + ((size_t)e * D_ + n0 + r0) * F_ + colk;
    const u16* bgp1 = w2t + ((size_t)e * D_ + n0 + r1) * F_ + colk;

    f32x4 acc[4][4];
    #pragma unroll
    for (int i = 0; i < 4; i++)
        #pragma unroll
        for (int j = 0; j < 4; j++) acc[i][j] = (f32x4){0.f, 0.f, 0.f, 0.f};

    int wm = (w >> 1) * 64, wn = (w & 1) * 64;
    int fm = lane & 15, k8 = (lane >> 4) * 8;

    for (int kk = 0; kk < F_; kk += 32) {
        async16(agp0 + kk, al0);
        async16(agp1 + kk, al1);
        async16(bgp0 + kk, bl0);
        async16(bgp1 + kk, bl1);
        __syncthreads();
        bf16x8 af[4], bfr[4];
        #pragma unroll
        for (int i = 0; i < 4; i++)
            af[i] = *(const bf16x8*)&As[(wm + i * 16 + fm) * 32 + k8];
        #pragma unroll
        for (int j = 0; j < 4; j++)
            bfr[j] = *(const bf16x8*)&Bs[(wn + j * 16 + fm) * 32 + k8];
        #pragma unroll
        for (int i = 0; i < 4; i++)
            #pragma unroll
            for (int j = 0; j < 4; j++)
                acc[i][j] = __builtin_amdgcn_mfma_f32_16x16x32_bf16(af[i], bfr[j], acc[i][j], 0, 0, 0);
        __syncthreads();
    }

    int rbase = (lane >> 4) * 4;
    #pragma unroll
    for (int j = 0; j < 4; j++) {
        int d = n0 + wn + j * 16 + fm;
        float bias = b2[e * D_ + d];
        #pragma unroll
        for (int i = 0; i < 4; i++) {
            #pragma unroll
            for (int r = 0; r < 4; r++) {
                int m = m0 + wm + i * 16 + rbase + r;
                if (m < cnt) {
                    float wgt = assign_weight[off + m];
                    y[(size_t)(off + m) * D_ + d] = (acc[i][j][r] + bias) * wgt;
                }
            }
        }
    }
}

// ---------------- combine: out[t] = y[pos0[t]] + y[pos1[t]] ----------------
__global__ void k_combine(const float* __restrict__ y, const int* __restrict__ pos,
                          float* __restrict__ out)
{
    int g = blockIdx.x * 256 + threadIdx.x;    // NTOK*192 threads (float4 per thread)
    int t = g / 192, c = g - t * 192;
    int p0 = pos[t * 2], p1 = pos[t * 2 + 1];
    const float4* y4 = (const float4*)y;
    float4 a = y4[(size_t)p0 * 192 + c];
    float4 b = y4[(size_t)p1 * 192 + c];
    float4 o = {a.x + b.x, a.y + b.y, a.z + b.z, a.w + b.w};
    ((float4*)out)[g] = o;
}

extern "C" void kernel_launch(void* const* d_in, const int* in_sizes, int n_in,
                              void* d_out, int out_size, void* d_ws, size_t ws_size,
                              hipStream_t stream)
{
    const float* x  = (const float*)d_in[0];
    const float* Wr = (const float*)d_in[1];
    const float* W1 = (const float*)d_in[2];
    const float* b1 = (const float*)d_in[3];
    const float* W2 = (const float*)d_in[4];
    const float* b2 = (const float*)d_in[5];
    float* out = (float*)d_out;

    char* base = (char*)d_ws;
    size_t o = 0;
    auto alloc = [&](size_t bytes) {
        char* r = base + o;
        o += (bytes + 255) & ~(size_t)255;
        return r;
    };
    int*   counts        = (int*)  alloc(E_ * 4);
    int*   cursors       = (int*)  alloc(E_ * 4);
    int*   offsets       = (int*)  alloc(E_ * 4);
    float* usage_part    = (float*)alloc((size_t)RBLK * E_ * 4);
    float* z_part        = (float*)alloc((size_t)RBLK * 4);
    int*   hist_part     = (int*)  alloc((size_t)RBLK * E_ * 4);
    int*   tk_idx        = (int*)  alloc((size_t)NTOK * 2 * 4);
    float* tk_w          = (float*)alloc((size_t)NTOK * 2 * 4);
    int*   pos           = (int*)  alloc((size_t)NTOK * 2 * 4);
    int*   assign_token  = (int*)  alloc((size_t)NASSIGN * 4);
    float* assign_weight = (float*)alloc((size_t)NASSIGN * 4);
    u16*   xb            = (u16*)  alloc((size_t)NTOK * D_ * 2);
    u16*   w1t           = (u16*)  alloc((size_t)E_ * F_ * D_ * 2);
    u16*   w2t           = (u16*)  alloc((size_t)E_ * D_ * F_ * 2);
    u16*   hbuf          = (u16*)  alloc((size_t)NASSIGN * F_ * 2);
    float* y             = (float*)alloc((size_t)NASSIGN * D_ * 4);  // keep after hbuf (over-read guard)

    k_init<<<dim3(1), dim3(64), 0, stream>>>(cursors);
    k_cvt_x<<<dim3(NTOK * D_ / 1024), dim3(256), 0, stream>>>(x, xb);
    k_tcvt<<<dim3(F_ / 32, D_ / 32, E_), dim3(256), 0, stream>>>(W1, w1t, D_, F_);
    k_tcvt<<<dim3(D_ / 32, F_ / 32, E_), dim3(256), 0, stream>>>(W2, w2t, F_, D_);
    k_router<<<dim3(RBLK), dim3(256), 0, stream>>>(x, Wr, usage_part, z_part, hist_part, tk_idx, tk_w);
    k_finalize<<<dim3(1), dim3(256), 0, stream>>>(usage_part, z_part, hist_part, counts, offsets,
                                                  out + (size_t)NTOK * D_);
    k_fill<<<dim3(FBLK), dim3(256), 0, stream>>>(tk_idx, tk_w, offsets, cursors, assign_token, assign_weight, pos);
    k_gemm1<<<dim3(E_ * 64, F_ / 128), dim3(256), 0, stream>>>(xb, w1t, b1, counts, offsets, assign_token, hbuf);
    k_gemm2<<<dim3(E_ * 64, D_ / 128), dim3(256), 0, stream>>>(hbuf, w2t, b2, counts, offsets, assign_weight, y);
    k_combine<<<dim3(NTOK * D_ / 1024), dim3(256), 0, stream>>>(y, pos, out);
}

// Round 4
// 623.978 us; speedup vs baseline: 2.7559x; 1.2232x over previous
//
#include <hip/hip_runtime.h>
#include <cstdint>
#include <cstddef>

#define B_ 4
#define S_ 2048
#define D_ 768
#define F_ 3072
#define E_ 8
#define NTOK (B_*S_)        // 8192
#define NASSIGN (NTOK*2)    // 16384 (every token has exactly 2 experts)
#define RBLK 256            // router blocks (32 tokens each)
#define FBLK 32             // fill blocks (256 tokens each)
#define MAXTILE 136         // max m-tiles: 128 + 8 rounding

typedef unsigned short u16;
typedef __attribute__((ext_vector_type(8))) __bf16 bf16x8;
typedef __attribute__((ext_vector_type(4))) float f32x4;

__device__ __forceinline__ u16 f2bf(float f) {
    unsigned int u = __builtin_bit_cast(unsigned int, f);
    u += 0x7fffu + ((u >> 16) & 1u);   // RNE
    return (u16)(u >> 16);
}

// global->LDS async copy, 16B/lane. lds base MUST be wave-uniform (m104/m108):
// HW writes lane i at lds + 16*i.
__device__ __forceinline__ void async16(const void* g, void* l) {
    __builtin_amdgcn_global_load_lds(
        (const __attribute__((address_space(1))) unsigned int*)g,
        (__attribute__((address_space(3))) unsigned int*)l, 16, 0, 0);
}

// exact-gelu x*Phi(x) via A&S 7.1.26 erf (|err|<=1.5e-7), branch-free
__device__ __forceinline__ float gelu_f(float v) {
    float z = v * 0.70710678f;
    float a = fabsf(z);
    float t = __builtin_amdgcn_rcpf(1.0f + 0.3275911f * a);
    float poly = t * (0.254829592f + t * (-0.284496736f + t * (1.421413741f +
                 t * (-1.453152027f + t * 1.061405429f))));
    float e = __expf(-z * z);
    float erf_z = copysignf(1.0f - poly * e, z);
    return 0.5f * v * (1.0f + erf_z);
}

// ---------------- init (zero cursors only) ----------------
__global__ void k_init(int* cursors) {
    int t = threadIdx.x;
    if (t < E_) cursors[t] = 0;
}

// ---------------- x fp32 -> bf16 ----------------
__global__ void k_cvt_x(const float* __restrict__ x, u16* __restrict__ xb) {
    int id = blockIdx.x * 256 + threadIdx.x;     // NTOK*D_/4 threads
    float4 v = ((const float4*)x)[id];
    ushort4 o;
    o.x = f2bf(v.x); o.y = f2bf(v.y); o.z = f2bf(v.z); o.w = f2bf(v.w);
    ((ushort4*)xb)[id] = o;
}

// ------------- weight transpose+convert: in[e][R][C] f32 -> out[e][C][R] bf16 -------------
// 32x32 tile, float4 loads, ushort4 stores
__global__ void k_tcvt(const float* __restrict__ in, u16* __restrict__ out, int R, int C) {
    __shared__ u16 t[32][33];
    int e = blockIdx.z;
    int c0 = blockIdx.x * 32, r0 = blockIdx.y * 32;
    int tx = threadIdx.x & 7;      // col group (4 cols each)
    int ty = threadIdx.x >> 3;     // row 0..31
    const float* ip = in + (size_t)e * R * C + (size_t)(r0 + ty) * C + c0 + tx * 4;
    float4 v = *(const float4*)ip;
    t[tx * 4 + 0][ty] = f2bf(v.x);
    t[tx * 4 + 1][ty] = f2bf(v.y);
    t[tx * 4 + 2][ty] = f2bf(v.z);
    t[tx * 4 + 3][ty] = f2bf(v.w);
    __syncthreads();
    u16* op = out + (size_t)e * C * R + (size_t)(c0 + ty) * R + r0 + tx * 4;
    ushort4 o;
    o.x = t[ty][tx * 4 + 0]; o.y = t[ty][tx * 4 + 1];
    o.z = t[ty][tx * 4 + 2]; o.w = t[ty][tx * 4 + 3];
    *(ushort4*)op = o;
}

// ---------------- router: logits, softmax, top-2; per-block partials, NO global atomics ----------------
__global__ __launch_bounds__(256) void k_router(
    const float* __restrict__ x, const float* __restrict__ Wr,
    float* __restrict__ usage_part,   // [RBLK][E_]
    float* __restrict__ z_part,       // [RBLK]
    int*   __restrict__ hist_part,    // [RBLK][E_]
    int* __restrict__ tk_idx, float* __restrict__ tk_w)
{
    __shared__ float wrt[E_ * D_];    // Wr transposed: [e][d]
    __shared__ float s_usage[E_];
    __shared__ float s_z;
    __shared__ int   s_hist[E_];
    int tid = threadIdx.x;
    for (int i = tid; i < E_ * D_; i += 256) {
        int d = i >> 3, e = i & 7;
        wrt[e * D_ + d] = Wr[i];
    }
    if (tid < E_) { s_usage[tid] = 0.f; s_hist[tid] = 0; }
    if (tid == 0) s_z = 0.f;
    __syncthreads();

    int w = tid >> 6, lane = tid & 63;
    float u_acc[E_];
    #pragma unroll
    for (int e = 0; e < E_; e++) u_acc[e] = 0.f;
    float z_acc = 0.f;

    for (int it = 0; it < 8; it++) {
        int tok = blockIdx.x * 32 + it * 4 + w;   // one wave per token
        float acc[E_];
        #pragma unroll
        for (int e = 0; e < E_; e++) acc[e] = 0.f;
        const float* xr = x + (size_t)tok * D_;
        for (int d = lane; d < D_; d += 64) {
            float xv = xr[d];
            #pragma unroll
            for (int e = 0; e < E_; e++) acc[e] += xv * wrt[e * D_ + d];
        }
        #pragma unroll
        for (int off = 32; off > 0; off >>= 1) {
            #pragma unroll
            for (int e = 0; e < E_; e++) acc[e] += __shfl_down(acc[e], off);
        }
        if (lane == 0) {
            float m = acc[0];
            #pragma unroll
            for (int e = 1; e < E_; e++) m = fmaxf(m, acc[e]);
            float p[E_], s = 0.f;
            #pragma unroll
            for (int e = 0; e < E_; e++) { p[e] = expf(acc[e] - m); s += p[e]; }
            float inv = 1.f / s;
            #pragma unroll
            for (int e = 0; e < E_; e++) { p[e] *= inv; u_acc[e] += p[e]; }
            float lse = m + logf(s);
            z_acc += lse * lse;
            int i1 = 0;
            for (int e = 1; e < E_; e++) if (p[e] > p[i1]) i1 = e;
            int i2 = -1;
            for (int e = 0; e < E_; e++) {
                if (e == i1) continue;
                if (i2 < 0 || p[e] > p[i2]) i2 = e;
            }
            float denom = p[i1] + p[i2] + 1e-8f;
            tk_idx[tok * 2 + 0] = i1; tk_idx[tok * 2 + 1] = i2;
            tk_w[tok * 2 + 0] = p[i1] / denom;
            tk_w[tok * 2 + 1] = p[i2] / denom;
            atomicAdd(&s_hist[i1], 1); atomicAdd(&s_hist[i2], 1);   // LDS atomics
        }
    }
    if (lane == 0) {
        #pragma unroll
        for (int e = 0; e < E_; e++) atomicAdd(&s_usage[e], u_acc[e]);
        atomicAdd(&s_z, z_acc);
    }
    __syncthreads();
    if (tid < E_) {
        usage_part[blockIdx.x * E_ + tid] = s_usage[tid];
        hist_part[blockIdx.x * E_ + tid]  = s_hist[tid];
    }
    if (tid == 0) z_part[blockIdx.x] = s_z;
}

// ---------------- reduce partials -> counts/offsets/tile-list + scalar losses ----------------
__global__ __launch_bounds__(256) void k_finalize(
    const float* __restrict__ usage_part, const float* __restrict__ z_part,
    const int* __restrict__ hist_part,
    int* __restrict__ counts, int* __restrict__ offsets,
    int* __restrict__ tile_list,      // [0]=ntiles, [1+i]=(m0<<8)|e
    float* __restrict__ out_scalars)
{
    __shared__ float s_u[E_];
    __shared__ float s_z;
    __shared__ int   s_h[E_];
    int tid = threadIdx.x;
    if (tid < E_) { s_u[tid] = 0.f; s_h[tid] = 0; }
    if (tid == 0) s_z = 0.f;
    __syncthreads();

    float u[E_]; int h[E_];
    #pragma unroll
    for (int e = 0; e < E_; e++) { u[e] = usage_part[tid * E_ + e]; h[e] = hist_part[tid * E_ + e]; }
    float z = z_part[tid];
    #pragma unroll
    for (int off = 32; off > 0; off >>= 1) {
        #pragma unroll
        for (int e = 0; e < E_; e++) {
            u[e] += __shfl_down(u[e], off);
            h[e] += __shfl_down(h[e], off);
        }
        z += __shfl_down(z, off);
    }
    if ((tid & 63) == 0) {
        #pragma unroll
        for (int e = 0; e < E_; e++) { atomicAdd(&s_u[e], u[e]); atomicAdd(&s_h[e], h[e]); }
        atomicAdd(&s_z, z);
    }
    __syncthreads();
    if (tid == 0) {
        int o = 0, nt = 0;
        for (int e = 0; e < E_; e++) {
            int c = s_h[e];
            counts[e] = c; offsets[e] = o; o += c;
            for (int m0 = 0; m0 < c; m0 += 128) tile_list[1 + nt++] = (m0 << 8) | e;
        }
        tile_list[0] = nt;
        float uu[E_], mean = 0.f;
        for (int e = 0; e < E_; e++) { uu[e] = s_u[e] / (float)NTOK; mean += uu[e]; }
        mean /= (float)E_;
        float var = 0.f;
        for (int e = 0; e < E_; e++) { float d = uu[e] - mean; var += d * d; }
        var /= (float)E_;
        out_scalars[0] = var / (mean * mean + 1e-8f) * (float)E_ * 0.01f;  // lb_loss
        out_scalars[1] = (s_z / (float)NTOK) * 0.001f;                      // z_loss
    }
}

// ---------------- build compact per-expert assignment lists (block-local ranks) ----------------
__global__ __launch_bounds__(256) void k_fill(
    const int* __restrict__ tk_idx, const float* __restrict__ tk_w,
    const int* __restrict__ offsets, int* __restrict__ cursors,
    int* __restrict__ assign_token, float* __restrict__ assign_weight,
    int* __restrict__ pos)
{
    __shared__ int l_cnt[E_];
    __shared__ int l_base[E_];
    int tid = threadIdx.x;
    if (tid < E_) l_cnt[tid] = 0;
    __syncthreads();
    int t = blockIdx.x * 256 + tid;
    int e0 = tk_idx[t * 2 + 0], e1 = tk_idx[t * 2 + 1];
    int r0 = atomicAdd(&l_cnt[e0], 1);            // LDS atomics
    int r1 = atomicAdd(&l_cnt[e1], 1);
    __syncthreads();
    if (tid < E_) l_base[tid] = atomicAdd(&cursors[tid], l_cnt[tid]);  // 8 global atomics/block
    __syncthreads();
    int row0 = offsets[e0] + l_base[e0] + r0;
    int row1 = offsets[e1] + l_base[e1] + r1;
    assign_token[row0] = t; assign_weight[row0] = tk_w[t * 2 + 0]; pos[t * 2 + 0] = row0;
    assign_token[row1] = t; assign_weight[row1] = tk_w[t * 2 + 1]; pos[t * 2 + 1] = row1;
}

// ---------------- GEMM1: h = gelu(gather(x) @ W1[e] + b1[e]), double-buffered bf16 MFMA ----------------
__global__ __launch_bounds__(256) void k_gemm1(
    const u16* __restrict__ xb, const u16* __restrict__ w1t,
    const float* __restrict__ b1,
    const int* __restrict__ counts, const int* __restrict__ offsets,
    const int* __restrict__ tile_list,
    const int* __restrict__ assign_token, u16* __restrict__ h)
{
    int nt = tile_list[0];
    if ((int)blockIdx.x >= nt) return;
    int packed = tile_list[1 + blockIdx.x];
    int e = packed & 0xff;
    int m0 = packed >> 8;
    int cnt = counts[e];
    int off = offsets[e];
    int n0 = blockIdx.y * 128;

    __shared__ __align__(16) u16 As[2][128 * 32];   // [m][k] K-major, double-buffered
    __shared__ __align__(16) u16 Bs[2][128 * 32];

    int tid = threadIdx.x;
    int w = tid >> 6, lane = tid & 63;
    int rA = lane >> 2;
    int colk = (lane & 3) * 8;
    int r0 = (w * 2 + 0) * 16 + rA;
    int r1 = (w * 2 + 1) * 16 + rA;

    // wave-uniform LDS chunk byte offsets (HW scatters lane i at +16*i)
    int c0b = __builtin_amdgcn_readfirstlane((w * 2 + 0) * 1024);
    int c1b = __builtin_amdgcn_readfirstlane((w * 2 + 1) * 1024);

    int g0 = m0 + r0; if (g0 > cnt - 1) g0 = cnt - 1;
    int g1 = m0 + r1; if (g1 > cnt - 1) g1 = cnt - 1;
    const u16* agp0 = xb + (size_t)assign_token[off + g0] * D_ + colk;
    const u16* agp1 = xb + (size_t)assign_token[off + g1] * D_ + colk;
    const u16* bgp0 = w1t + ((size_t)e * F_ + n0 + r0) * D_ + colk;
    const u16* bgp1 = w1t + ((size_t)e * F_ + n0 + r1) * D_ + colk;

    f32x4 acc[4][4];
    #pragma unroll
    for (int i = 0; i < 4; i++)
        #pragma unroll
        for (int j = 0; j < 4; j++) acc[i][j] = (f32x4){0.f, 0.f, 0.f, 0.f};

    int wm = (w >> 1) * 64, wn = (w & 1) * 64;
    int fm = lane & 15, k8 = (lane >> 4) * 8;

    #define STAGE1(buf, kk) do { \
        async16(agp0 + (kk), (char*)As[buf] + c0b); \
        async16(agp1 + (kk), (char*)As[buf] + c1b); \
        async16(bgp0 + (kk), (char*)Bs[buf] + c0b); \
        async16(bgp1 + (kk), (char*)Bs[buf] + c1b); \
    } while (0)
    #define COMPUTE1(buf) do { \
        bf16x8 af[4], bfr[4]; \
        _Pragma("unroll") \
        for (int i = 0; i < 4; i++) af[i] = *(const bf16x8*)&As[buf][(wm + i * 16 + fm) * 32 + k8]; \
        _Pragma("unroll") \
        for (int j = 0; j < 4; j++) bfr[j] = *(const bf16x8*)&Bs[buf][(wn + j * 16 + fm) * 32 + k8]; \
        _Pragma("unroll") \
        for (int i = 0; i < 4; i++) \
            _Pragma("unroll") \
            for (int j = 0; j < 4; j++) \
                acc[i][j] = __builtin_amdgcn_mfma_f32_16x16x32_bf16(af[i], bfr[j], acc[i][j], 0, 0, 0); \
    } while (0)

    STAGE1(0, 0);
    __syncthreads();
    for (int kk = 0; kk < D_; kk += 64) {          // pairs of 32-chunks; D_/32 even
        STAGE1(1, kk + 32);
        COMPUTE1(0);
        __syncthreads();
        if (kk + 64 < D_) STAGE1(0, kk + 64);
        COMPUTE1(1);
        __syncthreads();
    }
    #undef STAGE1
    #undef COMPUTE1

    int rbase = (lane >> 4) * 4;
    #pragma unroll
    for (int j = 0; j < 4; j++) {
        int f = n0 + wn + j * 16 + fm;
        float bias = b1[e * F_ + f];
        #pragma unroll
        for (int i = 0; i < 4; i++) {
            #pragma unroll
            for (int r = 0; r < 4; r++) {
                int m = m0 + wm + i * 16 + rbase + r;
                if (m < cnt) {
                    float v = acc[i][j][r] + bias;
                    h[(size_t)(off + m) * F_ + f] = f2bf(gelu_f(v));
                }
            }
        }
    }
}

// ---------------- GEMM2: y = (h @ W2[e] + b2[e]) * assign_weight, double-buffered ----------------
__global__ __launch_bounds__(256) void k_gemm2(
    const u16* __restrict__ h, const u16* __restrict__ w2t,
    const float* __restrict__ b2,
    const int* __restrict__ counts, const int* __restrict__ offsets,
    const int* __restrict__ tile_list,
    const float* __restrict__ assign_weight, float* __restrict__ y)
{
    int nt = tile_list[0];
    if ((int)blockIdx.x >= nt) return;
    int packed = tile_list[1 + blockIdx.x];
    int e = packed & 0xff;
    int m0 = packed >> 8;
    int cnt = counts[e];
    int off = offsets[e];
    int n0 = blockIdx.y * 128;

    __shared__ __align__(16) u16 As[2][128 * 32];
    __shared__ __align__(16) u16 Bs[2][128 * 32];

    int tid = threadIdx.x;
    int w = tid >> 6, lane = tid & 63;
    int rA = lane >> 2;
    int colk = (lane & 3) * 8;
    int r0 = (w * 2 + 0) * 16 + rA;
    int r1 = (w * 2 + 1) * 16 + rA;

    int c0b = __builtin_amdgcn_readfirstlane((w * 2 + 0) * 1024);
    int c1b = __builtin_amdgcn_readfirstlane((w * 2 + 1) * 1024);

    // rows beyond cnt over-read into the y region of ws (harmless, masked at store)
    const u16* agp0 = h + (size_t)(off + m0 + r0) * F_ + colk;
    const u16* agp1 = h + (size_t)(off + m0 + r1) * F_ + colk;
    const u16* bgp0 = w2t + ((size_t)e * D_ + n0 + r0) * F_ + colk;
    const u16* bgp1 = w2t + ((size_t)e * D_ + n0 + r1) * F_ + colk;

    f32x4 acc[4][4];
    #pragma unroll
    for (int i = 0; i < 4; i++)
        #pragma unroll
        for (int j = 0; j < 4; j++) acc[i][j] = (f32x4){0.f, 0.f, 0.f, 0.f};

    int wm = (w >> 1) * 64, wn = (w & 1) * 64;
    int fm = lane & 15, k8 = (lane >> 4) * 8;

    #define STAGE2(buf, kk) do { \
        async16(agp0 + (kk), (char*)As[buf] + c0b); \
        async16(agp1 + (kk), (char*)As[buf] + c1b); \
        async16(bgp0 + (kk), (char*)Bs[buf] + c0b); \
        async16(bgp1 + (kk), (char*)Bs[buf] + c1b); \
    } while (0)
    #define COMPUTE2(buf) do { \
        bf16x8 af[4], bfr[4]; \
        _Pragma("unroll") \
        for (int i = 0; i < 4; i++) af[i] = *(const bf16x8*)&As[buf][(wm + i * 16 + fm) * 32 + k8]; \
        _Pragma("unroll") \
        for (int j = 0; j < 4; j++) bfr[j] = *(const bf16x8*)&Bs[buf][(wn + j * 16 + fm) * 32 + k8]; \
        _Pragma("unroll") \
        for (int i = 0; i < 4; i++) \
            _Pragma("unroll") \
            for (int j = 0; j < 4; j++) \
                acc[i][j] = __builtin_amdgcn_mfma_f32_16x16x32_bf16(af[i], bfr[j], acc[i][j], 0, 0, 0); \
    } while (0)

    STAGE2(0, 0);
    __syncthreads();
    for (int kk = 0; kk < F_; kk += 64) {          // F_/32 even
        STAGE2(1, kk + 32);
        COMPUTE2(0);
        __syncthreads();
        if (kk + 64 < F_) STAGE2(0, kk + 64);
        COMPUTE2(1);
        __syncthreads();
    }
    #undef STAGE2
    #undef COMPUTE2

    int rbase = (lane >> 4) * 4;
    #pragma unroll
    for (int j = 0; j < 4; j++) {
        int d = n0 + wn + j * 16 + fm;
        float bias = b2[e * D_ + d];
        #pragma unroll
        for (int i = 0; i < 4; i++) {
            #pragma unroll
            for (int r = 0; r < 4; r++) {
                int m = m0 + wm + i * 16 + rbase + r;
                if (m < cnt) {
                    float wgt = assign_weight[off + m];
                    y[(size_t)(off + m) * D_ + d] = (acc[i][j][r] + bias) * wgt;
                }
            }
        }
    }
}

// ---------------- combine: out[t] = y[pos0[t]] + y[pos1[t]] ----------------
__global__ void k_combine(const float* __restrict__ y, const int* __restrict__ pos,
                          float* __restrict__ out)
{
    int g = blockIdx.x * 256 + threadIdx.x;    // NTOK*192 threads (float4 per thread)
    int t = g / 192, c = g - t * 192;
    int p0 = pos[t * 2], p1 = pos[t * 2 + 1];
    const float4* y4 = (const float4*)y;
    float4 a = y4[(size_t)p0 * 192 + c];
    float4 b = y4[(size_t)p1 * 192 + c];
    float4 o = {a.x + b.x, a.y + b.y, a.z + b.z, a.w + b.w};
    ((float4*)out)[g] = o;
}

extern "C" void kernel_launch(void* const* d_in, const int* in_sizes, int n_in,
                              void* d_out, int out_size, void* d_ws, size_t ws_size,
                              hipStream_t stream)
{
    const float* x  = (const float*)d_in[0];
    const float* Wr = (const float*)d_in[1];
    const float* W1 = (const float*)d_in[2];
    const float* b1 = (const float*)d_in[3];
    const float* W2 = (const float*)d_in[4];
    const float* b2 = (const float*)d_in[5];
    float* out = (float*)d_out;

    char* base = (char*)d_ws;
    size_t o = 0;
    auto alloc = [&](size_t bytes) {
        char* r = base + o;
        o += (bytes + 255) & ~(size_t)255;
        return r;
    };
    int*   counts        = (int*)  alloc(E_ * 4);
    int*   cursors       = (int*)  alloc(E_ * 4);
    int*   offsets       = (int*)  alloc(E_ * 4);
    int*   tile_list     = (int*)  alloc(256 * 4);
    float* usage_part    = (float*)alloc((size_t)RBLK * E_ * 4);
    float* z_part        = (float*)alloc((size_t)RBLK * 4);
    int*   hist_part     = (int*)  alloc((size_t)RBLK * E_ * 4);
    int*   tk_idx        = (int*)  alloc((size_t)NTOK * 2 * 4);
    float* tk_w          = (float*)alloc((size_t)NTOK * 2 * 4);
    int*   pos           = (int*)  alloc((size_t)NTOK * 2 * 4);
    int*   assign_token  = (int*)  alloc((size_t)NASSIGN * 4);
    float* assign_weight = (float*)alloc((size_t)NASSIGN * 4);
    u16*   xb            = (u16*)  alloc((size_t)NTOK * D_ * 2);
    u16*   w1t           = (u16*)  alloc((size_t)E_ * F_ * D_ * 2);
    u16*   w2t           = (u16*)  alloc((size_t)E_ * D_ * F_ * 2);
    u16*   hbuf          = (u16*)  alloc((size_t)NASSIGN * F_ * 2);
    float* y             = (float*)alloc((size_t)NASSIGN * D_ * 4);  // keep after hbuf (over-read guard)

    k_init<<<dim3(1), dim3(64), 0, stream>>>(cursors);
    k_cvt_x<<<dim3(NTOK * D_ / 1024), dim3(256), 0, stream>>>(x, xb);
    k_tcvt<<<dim3(F_ / 32, D_ / 32, E_), dim3(256), 0, stream>>>(W1, w1t, D_, F_);
    k_tcvt<<<dim3(D_ / 32, F_ / 32, E_), dim3(256), 0, stream>>>(W2, w2t, F_, D_);
    k_router<<<dim3(RBLK), dim3(256), 0, stream>>>(x, Wr, usage_part, z_part, hist_part, tk_idx, tk_w);
    k_finalize<<<dim3(1), dim3(256), 0, stream>>>(usage_part, z_part, hist_part, counts, offsets,
                                                  tile_list, out + (size_t)NTOK * D_);
    k_fill<<<dim3(FBLK), dim3(256), 0, stream>>>(tk_idx, tk_w, offsets, cursors, assign_token, assign_weight, pos);
    k_gemm1<<<dim3(MAXTILE, F_ / 128), dim3(256), 0, stream>>>(xb, w1t, b1, counts, offsets, tile_list,
                                                               assign_token, hbuf);
    k_gemm2<<<dim3(MAXTILE, D_ / 128), dim3(256), 0, stream>>>(hbuf, w2t, b2, counts, offsets, tile_list,
                                                               assign_weight, y);
    k_combine<<<dim3(NTOK * D_ / 1024), dim3(256), 0, stream>>>(y, pos, out);
}

// Round 5
// 611.644 us; speedup vs baseline: 2.8114x; 1.0202x over previous
//
#include <hip/hip_runtime.h>
#include <cstdint>
#include <cstddef>

#define B_ 4
#define S_ 2048
#define D_ 768
#define F_ 3072
#define E_ 8
#define NTOK (B_*S_)        // 8192
#define NASSIGN (NTOK*2)    // 16384 (every token has exactly 2 experts)
#define RBLK 256            // router blocks (32 tokens each)
#define FBLK 32             // fill blocks (256 tokens each)
#define MAXTILE 136         // max m-tiles: 128 + 8 rounding

typedef unsigned short u16;
typedef __attribute__((ext_vector_type(8))) __bf16 bf16x8;
typedef __attribute__((ext_vector_type(4))) float f32x4;

__device__ __forceinline__ u16 f2bf(float f) {
    unsigned int u = __builtin_bit_cast(unsigned int, f);
    u += 0x7fffu + ((u >> 16) & 1u);   // RNE
    return (u16)(u >> 16);
}

// global->LDS async copy, 16B/lane. lds base MUST be wave-uniform (m104/m108):
// HW writes lane i at lds + 16*i.
__device__ __forceinline__ void async16(const void* g, void* l) {
    __builtin_amdgcn_global_load_lds(
        (const __attribute__((address_space(1))) unsigned int*)g,
        (__attribute__((address_space(3))) unsigned int*)l, 16, 0, 0);
}

// exact-gelu x*Phi(x) via A&S 7.1.26 erf (|err|<=1.5e-7), branch-free
__device__ __forceinline__ float gelu_f(float v) {
    float z = v * 0.70710678f;
    float a = fabsf(z);
    float t = __builtin_amdgcn_rcpf(1.0f + 0.3275911f * a);
    float poly = t * (0.254829592f + t * (-0.284496736f + t * (1.421413741f +
                 t * (-1.453152027f + t * 1.061405429f))));
    float e = __expf(-z * z);
    float erf_z = copysignf(1.0f - poly * e, z);
    return 0.5f * v * (1.0f + erf_z);
}

// ---------------- init (zero cursors only) ----------------
__global__ void k_init(int* cursors) {
    int t = threadIdx.x;
    if (t < E_) cursors[t] = 0;
}

// ---------------- x fp32 -> bf16 ----------------
__global__ void k_cvt_x(const float* __restrict__ x, u16* __restrict__ xb) {
    int id = blockIdx.x * 256 + threadIdx.x;     // NTOK*D_/4 threads
    float4 v = ((const float4*)x)[id];
    ushort4 o;
    o.x = f2bf(v.x); o.y = f2bf(v.y); o.z = f2bf(v.z); o.w = f2bf(v.w);
    ((ushort4*)xb)[id] = o;
}

// ------------- weight transpose+convert: in[e][R][C] f32 -> out[e][C][R] bf16 -------------
__global__ void k_tcvt(const float* __restrict__ in, u16* __restrict__ out, int R, int C) {
    __shared__ u16 t[32][33];
    int e = blockIdx.z;
    int c0 = blockIdx.x * 32, r0 = blockIdx.y * 32;
    int tx = threadIdx.x & 7;      // col group (4 cols each)
    int ty = threadIdx.x >> 3;     // row 0..31
    const float* ip = in + (size_t)e * R * C + (size_t)(r0 + ty) * C + c0 + tx * 4;
    float4 v = *(const float4*)ip;
    t[tx * 4 + 0][ty] = f2bf(v.x);
    t[tx * 4 + 1][ty] = f2bf(v.y);
    t[tx * 4 + 2][ty] = f2bf(v.z);
    t[tx * 4 + 3][ty] = f2bf(v.w);
    __syncthreads();
    u16* op = out + (size_t)e * C * R + (size_t)(c0 + ty) * R + r0 + tx * 4;
    ushort4 o;
    o.x = t[ty][tx * 4 + 0]; o.y = t[ty][tx * 4 + 1];
    o.z = t[ty][tx * 4 + 2]; o.w = t[ty][tx * 4 + 3];
    *(ushort4*)op = o;
}

// ---------------- router ----------------
__global__ __launch_bounds__(256) void k_router(
    const float* __restrict__ x, const float* __restrict__ Wr,
    float* __restrict__ usage_part, float* __restrict__ z_part,
    int* __restrict__ hist_part,
    int* __restrict__ tk_idx, float* __restrict__ tk_w)
{
    __shared__ float wrt[E_ * D_];
    __shared__ float s_usage[E_];
    __shared__ float s_z;
    __shared__ int   s_hist[E_];
    int tid = threadIdx.x;
    for (int i = tid; i < E_ * D_; i += 256) {
        int d = i >> 3, e = i & 7;
        wrt[e * D_ + d] = Wr[i];
    }
    if (tid < E_) { s_usage[tid] = 0.f; s_hist[tid] = 0; }
    if (tid == 0) s_z = 0.f;
    __syncthreads();

    int w = tid >> 6, lane = tid & 63;
    float u_acc[E_];
    #pragma unroll
    for (int e = 0; e < E_; e++) u_acc[e] = 0.f;
    float z_acc = 0.f;

    for (int it = 0; it < 8; it++) {
        int tok = blockIdx.x * 32 + it * 4 + w;
        float acc[E_];
        #pragma unroll
        for (int e = 0; e < E_; e++) acc[e] = 0.f;
        const float* xr = x + (size_t)tok * D_;
        for (int d = lane; d < D_; d += 64) {
            float xv = xr[d];
            #pragma unroll
            for (int e = 0; e < E_; e++) acc[e] += xv * wrt[e * D_ + d];
        }
        #pragma unroll
        for (int off = 32; off > 0; off >>= 1) {
            #pragma unroll
            for (int e = 0; e < E_; e++) acc[e] += __shfl_down(acc[e], off);
        }
        if (lane == 0) {
            float m = acc[0];
            #pragma unroll
            for (int e = 1; e < E_; e++) m = fmaxf(m, acc[e]);
            float p[E_], s = 0.f;
            #pragma unroll
            for (int e = 0; e < E_; e++) { p[e] = expf(acc[e] - m); s += p[e]; }
            float inv = 1.f / s;
            #pragma unroll
            for (int e = 0; e < E_; e++) { p[e] *= inv; u_acc[e] += p[e]; }
            float lse = m + logf(s);
            z_acc += lse * lse;
            int i1 = 0;
            for (int e = 1; e < E_; e++) if (p[e] > p[i1]) i1 = e;
            int i2 = -1;
            for (int e = 0; e < E_; e++) {
                if (e == i1) continue;
                if (i2 < 0 || p[e] > p[i2]) i2 = e;
            }
            float denom = p[i1] + p[i2] + 1e-8f;
            tk_idx[tok * 2 + 0] = i1; tk_idx[tok * 2 + 1] = i2;
            tk_w[tok * 2 + 0] = p[i1] / denom;
            tk_w[tok * 2 + 1] = p[i2] / denom;
            atomicAdd(&s_hist[i1], 1); atomicAdd(&s_hist[i2], 1);
        }
    }
    if (lane == 0) {
        #pragma unroll
        for (int e = 0; e < E_; e++) atomicAdd(&s_usage[e], u_acc[e]);
        atomicAdd(&s_z, z_acc);
    }
    __syncthreads();
    if (tid < E_) {
        usage_part[blockIdx.x * E_ + tid] = s_usage[tid];
        hist_part[blockIdx.x * E_ + tid]  = s_hist[tid];
    }
    if (tid == 0) z_part[blockIdx.x] = s_z;
}

// ---------------- reduce partials -> counts/offsets/tile-list + scalar losses ----------------
__global__ __launch_bounds__(256) void k_finalize(
    const float* __restrict__ usage_part, const float* __restrict__ z_part,
    const int* __restrict__ hist_part,
    int* __restrict__ counts, int* __restrict__ offsets,
    int* __restrict__ tile_list,      // [0]=ntiles, [1+i]=(m0<<8)|e
    float* __restrict__ out_scalars)
{
    __shared__ float s_u[E_];
    __shared__ float s_z;
    __shared__ int   s_h[E_];
    int tid = threadIdx.x;
    if (tid < E_) { s_u[tid] = 0.f; s_h[tid] = 0; }
    if (tid == 0) s_z = 0.f;
    __syncthreads();

    float u[E_]; int h[E_];
    #pragma unroll
    for (int e = 0; e < E_; e++) { u[e] = usage_part[tid * E_ + e]; h[e] = hist_part[tid * E_ + e]; }
    float z = z_part[tid];
    #pragma unroll
    for (int off = 32; off > 0; off >>= 1) {
        #pragma unroll
        for (int e = 0; e < E_; e++) {
            u[e] += __shfl_down(u[e], off);
            h[e] += __shfl_down(h[e], off);
        }
        z += __shfl_down(z, off);
    }
    if ((tid & 63) == 0) {
        #pragma unroll
        for (int e = 0; e < E_; e++) { atomicAdd(&s_u[e], u[e]); atomicAdd(&s_h[e], h[e]); }
        atomicAdd(&s_z, z);
    }
    __syncthreads();
    if (tid == 0) {
        int o = 0, nt = 0;
        for (int e = 0; e < E_; e++) {
            int c = s_h[e];
            counts[e] = c; offsets[e] = o; o += c;
            for (int m0 = 0; m0 < c; m0 += 128) tile_list[1 + nt++] = (m0 << 8) | e;
        }
        tile_list[0] = nt;
        float uu[E_], mean = 0.f;
        for (int e = 0; e < E_; e++) { uu[e] = s_u[e] / (float)NTOK; mean += uu[e]; }
        mean /= (float)E_;
        float var = 0.f;
        for (int e = 0; e < E_; e++) { float d = uu[e] - mean; var += d * d; }
        var /= (float)E_;
        out_scalars[0] = var / (mean * mean + 1e-8f) * (float)E_ * 0.01f;  // lb_loss
        out_scalars[1] = (s_z / (float)NTOK) * 0.001f;                      // z_loss
    }
}

// ---------------- build compact per-expert assignment lists ----------------
__global__ __launch_bounds__(256) void k_fill(
    const int* __restrict__ tk_idx, const float* __restrict__ tk_w,
    const int* __restrict__ offsets, int* __restrict__ cursors,
    int* __restrict__ assign_token, float* __restrict__ assign_weight)
{
    __shared__ int l_cnt[E_];
    __shared__ int l_base[E_];
    int tid = threadIdx.x;
    if (tid < E_) l_cnt[tid] = 0;
    __syncthreads();
    int t = blockIdx.x * 256 + tid;
    int e0 = tk_idx[t * 2 + 0], e1 = tk_idx[t * 2 + 1];
    int r0 = atomicAdd(&l_cnt[e0], 1);
    int r1 = atomicAdd(&l_cnt[e1], 1);
    __syncthreads();
    if (tid < E_) l_base[tid] = atomicAdd(&cursors[tid], l_cnt[tid]);
    __syncthreads();
    int row0 = offsets[e0] + l_base[e0] + r0;
    int row1 = offsets[e1] + l_base[e1] + r1;
    assign_token[row0] = t; assign_weight[row0] = tk_w[t * 2 + 0];
    assign_token[row1] = t; assign_weight[row1] = tk_w[t * 2 + 1];
}

// ---------------- GEMM1: h = gelu(gather(x) @ W1[e] + b1[e]) ----------------
// K-major XOR-swizzled staging; coalesced LDS-transpose epilogue.
__global__ __launch_bounds__(256) void k_gemm1(
    const u16* __restrict__ xb, const u16* __restrict__ w1t,
    const float* __restrict__ b1,
    const int* __restrict__ counts, const int* __restrict__ offsets,
    const int* __restrict__ tile_list,
    const int* __restrict__ assign_token, u16* __restrict__ h)
{
    int nt = tile_list[0];
    if ((int)blockIdx.x >= nt) return;
    int packed = tile_list[1 + blockIdx.x];
    int e = packed & 0xff;
    int m0 = packed >> 8;
    int cnt = counts[e];
    int off = offsets[e];
    int n0 = blockIdx.y * 128;

    __shared__ __align__(16) u16 SM[16384];   // As dbuf @0, Bs dbuf @8192 (u16 idx)
    char* smb = (char*)SM;

    int tid = threadIdx.x;
    int w = tid >> 6, lane = tid & 63;
    int rA = lane >> 2;
    // XOR-swizzled k-chunk for staging: lane (rA,c) loads global chunk c^(rA&3)
    int colk = ((lane & 3) ^ (rA & 3)) * 8;
    int r0 = (w * 2 + 0) * 16 + rA;
    int r1 = (w * 2 + 1) * 16 + rA;

    int c0b = __builtin_amdgcn_readfirstlane((w * 2 + 0) * 1024);
    int c1b = __builtin_amdgcn_readfirstlane((w * 2 + 1) * 1024);

    int g0 = m0 + r0; if (g0 > cnt - 1) g0 = cnt - 1;
    int g1 = m0 + r1; if (g1 > cnt - 1) g1 = cnt - 1;
    const u16* agp0 = xb + (size_t)assign_token[off + g0] * D_ + colk;
    const u16* agp1 = xb + (size_t)assign_token[off + g1] * D_ + colk;
    const u16* bgp0 = w1t + ((size_t)e * F_ + n0 + r0) * D_ + colk;
    const u16* bgp1 = w1t + ((size_t)e * F_ + n0 + r1) * D_ + colk;

    f32x4 acc[4][4];
    #pragma unroll
    for (int i = 0; i < 4; i++)
        #pragma unroll
        for (int j = 0; j < 4; j++) acc[i][j] = (f32x4){0.f, 0.f, 0.f, 0.f};

    int wm = (w >> 1) * 64, wn = (w & 1) * 64;
    int fm = lane & 15;
    int slot = ((lane >> 4) ^ (fm & 3)) * 8;   // swizzled fragment slot

    #define STAGE1(buf, kk) do { \
        async16(agp0 + (kk), smb + (buf) * 8192 + c0b); \
        async16(agp1 + (kk), smb + (buf) * 8192 + c1b); \
        async16(bgp0 + (kk), smb + 16384 + (buf) * 8192 + c0b); \
        async16(bgp1 + (kk), smb + 16384 + (buf) * 8192 + c1b); \
    } while (0)
    #define COMPUTE1(buf) do { \
        const u16* Ab = SM + (buf) * 4096; \
        const u16* Bb = SM + 8192 + (buf) * 4096; \
        bf16x8 af[4], bfr[4]; \
        _Pragma("unroll") \
        for (int i = 0; i < 4; i++) af[i] = *(const bf16x8*)&Ab[(wm + i * 16 + fm) * 32 + slot]; \
        _Pragma("unroll") \
        for (int j = 0; j < 4; j++) bfr[j] = *(const bf16x8*)&Bb[(wn + j * 16 + fm) * 32 + slot]; \
        _Pragma("unroll") \
        for (int i = 0; i < 4; i++) \
            _Pragma("unroll") \
            for (int j = 0; j < 4; j++) \
                acc[i][j] = __builtin_amdgcn_mfma_f32_16x16x32_bf16(af[i], bfr[j], acc[i][j], 0, 0, 0); \
    } while (0)

    STAGE1(0, 0);
    __syncthreads();
    for (int kk = 0; kk < D_; kk += 64) {
        STAGE1(1, kk + 32);
        COMPUTE1(0);
        __syncthreads();
        if (kk + 64 < D_) STAGE1(0, kk + 64);
        COMPUTE1(1);
        __syncthreads();
    }
    #undef STAGE1
    #undef COMPUTE1

    // ---- epilogue: gelu+cvt -> per-wave swizzled LDS tile -> coalesced uint4 stores ----
    int rbase = (lane >> 4) * 4;
    u16* tb = SM + w * 4096;          // 64x64 u16 (8 KB), XOR-swizzled by (m&7)
    float biasv[4];
    #pragma unroll
    for (int j = 0; j < 4; j++) biasv[j] = b1[e * F_ + n0 + wn + j * 16 + fm];
    #pragma unroll
    for (int i = 0; i < 4; i++)
        #pragma unroll
        for (int j = 0; j < 4; j++)
            #pragma unroll
            for (int r = 0; r < 4; r++) {
                int m_l = i * 16 + rbase + r;
                int f_l = j * 16 + fm;
                u16 q = f2bf(gelu_f(acc[i][j][r] + biasv[j]));
                tb[m_l * 64 + ((((f_l >> 3) ^ (m_l & 7)) << 3) | (f_l & 7))] = q;
            }
    __syncthreads();
    #pragma unroll
    for (int s = 0; s < 8; s++) {
        int m_l = s * 8 + (lane >> 3);
        int c = lane & 7;
        uint4 vv = *(const uint4*)&tb[m_l * 64 + ((c ^ (m_l & 7)) << 3)];
        int m = m0 + wm + m_l;
        if (m < cnt)
            *(uint4*)&h[(size_t)(off + m) * F_ + n0 + wn + c * 8] = vv;
    }
}

// ---------------- GEMM2: out[token] += (h @ W2[e] + b2[e]) * weight (atomic combine) ----------------
__global__ __launch_bounds__(256) void k_gemm2(
    const u16* __restrict__ h, const u16* __restrict__ w2t,
    const float* __restrict__ b2,
    const int* __restrict__ counts, const int* __restrict__ offsets,
    const int* __restrict__ tile_list,
    const int* __restrict__ assign_token, const float* __restrict__ assign_weight,
    float* __restrict__ out)
{
    int nt = tile_list[0];
    if ((int)blockIdx.x >= nt) return;
    int packed = tile_list[1 + blockIdx.x];
    int e = packed & 0xff;
    int m0 = packed >> 8;
    int cnt = counts[e];
    int off = offsets[e];
    int n0 = blockIdx.y * 128;

    __shared__ __align__(16) u16 SM[16384];
    char* smb = (char*)SM;

    int tid = threadIdx.x;
    int w = tid >> 6, lane = tid & 63;
    int rA = lane >> 2;
    int colk = ((lane & 3) ^ (rA & 3)) * 8;
    int r0 = (w * 2 + 0) * 16 + rA;
    int r1 = (w * 2 + 1) * 16 + rA;

    int c0b = __builtin_amdgcn_readfirstlane((w * 2 + 0) * 1024);
    int c1b = __builtin_amdgcn_readfirstlane((w * 2 + 1) * 1024);

    // rows beyond cnt over-read hbuf slack rows (allocated), masked at store
    const u16* agp0 = h + (size_t)(off + m0 + r0) * F_ + colk;
    const u16* agp1 = h + (size_t)(off + m0 + r1) * F_ + colk;
    const u16* bgp0 = w2t + ((size_t)e * D_ + n0 + r0) * F_ + colk;
    const u16* bgp1 = w2t + ((size_t)e * D_ + n0 + r1) * F_ + colk;

    f32x4 acc[4][4];
    #pragma unroll
    for (int i = 0; i < 4; i++)
        #pragma unroll
        for (int j = 0; j < 4; j++) acc[i][j] = (f32x4){0.f, 0.f, 0.f, 0.f};

    int wm = (w >> 1) * 64, wn = (w & 1) * 64;
    int fm = lane & 15;
    int slot = ((lane >> 4) ^ (fm & 3)) * 8;

    #define STAGE2(buf, kk) do { \
        async16(agp0 + (kk), smb + (buf) * 8192 + c0b); \
        async16(agp1 + (kk), smb + (buf) * 8192 + c1b); \
        async16(bgp0 + (kk), smb + 16384 + (buf) * 8192 + c0b); \
        async16(bgp1 + (kk), smb + 16384 + (buf) * 8192 + c1b); \
    } while (0)
    #define COMPUTE2(buf) do { \
        const u16* Ab = SM + (buf) * 4096; \
        const u16* Bb = SM + 8192 + (buf) * 4096; \
        bf16x8 af[4], bfr[4]; \
        _Pragma("unroll") \
        for (int i = 0; i < 4; i++) af[i] = *(const bf16x8*)&Ab[(wm + i * 16 + fm) * 32 + slot]; \
        _Pragma("unroll") \
        for (int j = 0; j < 4; j++) bfr[j] = *(const bf16x8*)&Bb[(wn + j * 16 + fm) * 32 + slot]; \
        _Pragma("unroll") \
        for (int i = 0; i < 4; i++) \
            _Pragma("unroll") \
            for (int j = 0; j < 4; j++) \
                acc[i][j] = __builtin_amdgcn_mfma_f32_16x16x32_bf16(af[i], bfr[j], acc[i][j], 0, 0, 0); \
    } while (0)

    STAGE2(0, 0);
    __syncthreads();
    for (int kk = 0; kk < F_; kk += 64) {
        STAGE2(1, kk + 32);
        COMPUTE2(0);
        __syncthreads();
        if (kk + 64 < F_) STAGE2(0, kk + 64);
        COMPUTE2(1);
        __syncthreads();
    }
    #undef STAGE2
    #undef COMPUTE2

    int rbase = (lane >> 4) * 4;
    float biasv[4];
    #pragma unroll
    for (int j = 0; j < 4; j++) biasv[j] = b2[e * D_ + n0 + wn + j * 16 + fm];
    #pragma unroll
    for (int i = 0; i < 4; i++)
        #pragma unroll
        for (int r = 0; r < 4; r++) {
            int m = m0 + wm + i * 16 + rbase + r;
            if (m < cnt) {
                int t = assign_token[off + m];
                float wg = assign_weight[off + m];
                float* orow = out + (size_t)t * D_ + n0 + wn + fm;
                #pragma unroll
                for (int j = 0; j < 4; j++)
                    unsafeAtomicAdd(orow + j * 16, (acc[i][j][r] + biasv[j]) * wg);
            }
        }
}

extern "C" void kernel_launch(void* const* d_in, const int* in_sizes, int n_in,
                              void* d_out, int out_size, void* d_ws, size_t ws_size,
                              hipStream_t stream)
{
    const float* x  = (const float*)d_in[0];
    const float* Wr = (const float*)d_in[1];
    const float* W1 = (const float*)d_in[2];
    const float* b1 = (const float*)d_in[3];
    const float* W2 = (const float*)d_in[4];
    const float* b2 = (const float*)d_in[5];
    float* out = (float*)d_out;

    char* base = (char*)d_ws;
    size_t o = 0;
    auto alloc = [&](size_t bytes) {
        char* r = base + o;
        o += (bytes + 255) & ~(size_t)255;
        return r;
    };
    int*   counts        = (int*)  alloc(E_ * 4);
    int*   cursors       = (int*)  alloc(E_ * 4);
    int*   offsets       = (int*)  alloc(E_ * 4);
    int*   tile_list     = (int*)  alloc(256 * 4);
    float* usage_part    = (float*)alloc((size_t)RBLK * E_ * 4);
    float* z_part        = (float*)alloc((size_t)RBLK * 4);
    int*   hist_part     = (int*)  alloc((size_t)RBLK * E_ * 4);
    int*   tk_idx        = (int*)  alloc((size_t)NTOK * 2 * 4);
    float* tk_w          = (float*)alloc((size_t)NTOK * 2 * 4);
    int*   assign_token  = (int*)  alloc((size_t)NASSIGN * 4);
    float* assign_weight = (float*)alloc((size_t)NASSIGN * 4);
    u16*   xb            = (u16*)  alloc((size_t)NTOK * D_ * 2);
    u16*   w1t           = (u16*)  alloc((size_t)E_ * F_ * D_ * 2);
    u16*   w2t           = (u16*)  alloc((size_t)E_ * D_ * F_ * 2);
    u16*   hbuf          = (u16*)  alloc((size_t)(NASSIGN + 128) * F_ * 2);  // +128 over-read slack

    hipMemsetAsync(d_out, 0, (size_t)out_size * 4, stream);
    k_init<<<dim3(1), dim3(64), 0, stream>>>(cursors);
    k_cvt_x<<<dim3(NTOK * D_ / 1024), dim3(256), 0, stream>>>(x, xb);
    k_tcvt<<<dim3(F_ / 32, D_ / 32, E_), dim3(256), 0, stream>>>(W1, w1t, D_, F_);
    k_tcvt<<<dim3(D_ / 32, F_ / 32, E_), dim3(256), 0, stream>>>(W2, w2t, F_, D_);
    k_router<<<dim3(RBLK), dim3(256), 0, stream>>>(x, Wr, usage_part, z_part, hist_part, tk_idx, tk_w);
    k_finalize<<<dim3(1), dim3(256), 0, stream>>>(usage_part, z_part, hist_part, counts, offsets,
                                                  tile_list, out + (size_t)NTOK * D_);
    k_fill<<<dim3(FBLK), dim3(256), 0, stream>>>(tk_idx, tk_w, offsets, cursors, assign_token, assign_weight);
    k_gemm1<<<dim3(MAXTILE, F_ / 128), dim3(256), 0, stream>>>(xb, w1t, b1, counts, offsets, tile_list,
                                                               assign_token, hbuf);
    k_gemm2<<<dim3(MAXTILE, D_ / 128), dim3(256), 0, stream>>>(hbuf, w2t, b2, counts, offsets, tile_list,
                                                               assign_token, assign_weight, out);
}

// Round 6
// 607.213 us; speedup vs baseline: 2.8320x; 1.0073x over previous
//
#include <hip/hip_runtime.h>
#include <cstdint>
#include <cstddef>

#define B_ 4
#define S_ 2048
#define D_ 768
#define F_ 3072
#define E_ 8
#define NTOK (B_*S_)        // 8192
#define NASSIGN (NTOK*2)    // 16384 (every token has exactly 2 experts)
#define RBLK 256            // router blocks (32 tokens each)
#define FBLK 32             // fill blocks (256 tokens each)
#define MAXTILE 136         // max m-tiles: 8 XCDs x 17

typedef unsigned short u16;
typedef __attribute__((ext_vector_type(8))) __bf16 bf16x8;
typedef __attribute__((ext_vector_type(4))) float f32x4;

__device__ __forceinline__ u16 f2bf(float f) {
    unsigned int u = __builtin_bit_cast(unsigned int, f);
    u += 0x7fffu + ((u >> 16) & 1u);   // RNE
    return (u16)(u >> 16);
}

// global->LDS async copy, 16B/lane. lds base MUST be wave-uniform (m104/m108):
// HW writes lane i at lds + 16*i.
__device__ __forceinline__ void async16(const void* g, void* l) {
    __builtin_amdgcn_global_load_lds(
        (const __attribute__((address_space(1))) unsigned int*)g,
        (__attribute__((address_space(3))) unsigned int*)l, 16, 0, 0);
}

// exact-gelu x*Phi(x) via A&S 7.1.26 erf (|err|<=1.5e-7), branch-free
__device__ __forceinline__ float gelu_f(float v) {
    float z = v * 0.70710678f;
    float a = fabsf(z);
    float t = __builtin_amdgcn_rcpf(1.0f + 0.3275911f * a);
    float poly = t * (0.254829592f + t * (-0.284496736f + t * (1.421413741f +
                 t * (-1.453152027f + t * 1.061405429f))));
    float e = __expf(-z * z);
    float erf_z = copysignf(1.0f - poly * e, z);
    return 0.5f * v * (1.0f + erf_z);
}

// ---------------- init (zero cursors only) ----------------
__global__ void k_init(int* cursors) {
    int t = threadIdx.x;
    if (t < E_) cursors[t] = 0;
}

// ---------------- x fp32 -> bf16 ----------------
__global__ void k_cvt_x(const float* __restrict__ x, u16* __restrict__ xb) {
    int id = blockIdx.x * 256 + threadIdx.x;     // NTOK*D_/4 threads
    float4 v = ((const float4*)x)[id];
    ushort4 o;
    o.x = f2bf(v.x); o.y = f2bf(v.y); o.z = f2bf(v.z); o.w = f2bf(v.w);
    ((ushort4*)xb)[id] = o;
}

// ------------- weight transpose+convert: in[e][R][C] f32 -> out[e][C][R] bf16 -------------
__global__ void k_tcvt(const float* __restrict__ in, u16* __restrict__ out, int R, int C) {
    __shared__ u16 t[32][33];
    int e = blockIdx.z;
    int c0 = blockIdx.x * 32, r0 = blockIdx.y * 32;
    int tx = threadIdx.x & 7;      // col group (4 cols each)
    int ty = threadIdx.x >> 3;     // row 0..31
    const float* ip = in + (size_t)e * R * C + (size_t)(r0 + ty) * C + c0 + tx * 4;
    float4 v = *(const float4*)ip;
    t[tx * 4 + 0][ty] = f2bf(v.x);
    t[tx * 4 + 1][ty] = f2bf(v.y);
    t[tx * 4 + 2][ty] = f2bf(v.z);
    t[tx * 4 + 3][ty] = f2bf(v.w);
    __syncthreads();
    u16* op = out + (size_t)e * C * R + (size_t)(c0 + ty) * R + r0 + tx * 4;
    ushort4 o;
    o.x = t[ty][tx * 4 + 0]; o.y = t[ty][tx * 4 + 1];
    o.z = t[ty][tx * 4 + 2]; o.w = t[ty][tx * 4 + 3];
    *(ushort4*)op = o;
}

// ---------------- router ----------------
__global__ __launch_bounds__(256) void k_router(
    const float* __restrict__ x, const float* __restrict__ Wr,
    float* __restrict__ usage_part, float* __restrict__ z_part,
    int* __restrict__ hist_part,
    int* __restrict__ tk_idx, float* __restrict__ tk_w)
{
    __shared__ float wrt[E_ * D_];
    __shared__ float s_usage[E_];
    __shared__ float s_z;
    __shared__ int   s_hist[E_];
    int tid = threadIdx.x;
    for (int i = tid; i < E_ * D_; i += 256) {
        int d = i >> 3, e = i & 7;
        wrt[e * D_ + d] = Wr[i];
    }
    if (tid < E_) { s_usage[tid] = 0.f; s_hist[tid] = 0; }
    if (tid == 0) s_z = 0.f;
    __syncthreads();

    int w = tid >> 6, lane = tid & 63;
    float u_acc[E_];
    #pragma unroll
    for (int e = 0; e < E_; e++) u_acc[e] = 0.f;
    float z_acc = 0.f;

    for (int it = 0; it < 8; it++) {
        int tok = blockIdx.x * 32 + it * 4 + w;
        float acc[E_];
        #pragma unroll
        for (int e = 0; e < E_; e++) acc[e] = 0.f;
        const float* xr = x + (size_t)tok * D_;
        for (int d = lane; d < D_; d += 64) {
            float xv = xr[d];
            #pragma unroll
            for (int e = 0; e < E_; e++) acc[e] += xv * wrt[e * D_ + d];
        }
        #pragma unroll
        for (int off = 32; off > 0; off >>= 1) {
            #pragma unroll
            for (int e = 0; e < E_; e++) acc[e] += __shfl_down(acc[e], off);
        }
        if (lane == 0) {
            float m = acc[0];
            #pragma unroll
            for (int e = 1; e < E_; e++) m = fmaxf(m, acc[e]);
            float p[E_], s = 0.f;
            #pragma unroll
            for (int e = 0; e < E_; e++) { p[e] = expf(acc[e] - m); s += p[e]; }
            float inv = 1.f / s;
            #pragma unroll
            for (int e = 0; e < E_; e++) { p[e] *= inv; u_acc[e] += p[e]; }
            float lse = m + logf(s);
            z_acc += lse * lse;
            int i1 = 0;
            for (int e = 1; e < E_; e++) if (p[e] > p[i1]) i1 = e;
            int i2 = -1;
            for (int e = 0; e < E_; e++) {
                if (e == i1) continue;
                if (i2 < 0 || p[e] > p[i2]) i2 = e;
            }
            float denom = p[i1] + p[i2] + 1e-8f;
            tk_idx[tok * 2 + 0] = i1; tk_idx[tok * 2 + 1] = i2;
            tk_w[tok * 2 + 0] = p[i1] / denom;
            tk_w[tok * 2 + 1] = p[i2] / denom;
            atomicAdd(&s_hist[i1], 1); atomicAdd(&s_hist[i2], 1);
        }
    }
    if (lane == 0) {
        #pragma unroll
        for (int e = 0; e < E_; e++) atomicAdd(&s_usage[e], u_acc[e]);
        atomicAdd(&s_z, z_acc);
    }
    __syncthreads();
    if (tid < E_) {
        usage_part[blockIdx.x * E_ + tid] = s_usage[tid];
        hist_part[blockIdx.x * E_ + tid]  = s_hist[tid];
    }
    if (tid == 0) z_part[blockIdx.x] = s_z;
}

// ---------------- reduce partials -> counts/offsets/tile-list + scalar losses ----------------
__global__ __launch_bounds__(256) void k_finalize(
    const float* __restrict__ usage_part, const float* __restrict__ z_part,
    const int* __restrict__ hist_part,
    int* __restrict__ counts, int* __restrict__ offsets,
    int* __restrict__ tile_list,      // [0]=ntiles, [1+i]=(m0<<8)|e
    float* __restrict__ out_scalars)
{
    __shared__ float s_u[E_];
    __shared__ float s_z;
    __shared__ int   s_h[E_];
    int tid = threadIdx.x;
    if (tid < E_) { s_u[tid] = 0.f; s_h[tid] = 0; }
    if (tid == 0) s_z = 0.f;
    __syncthreads();

    float u[E_]; int h[E_];
    #pragma unroll
    for (int e = 0; e < E_; e++) { u[e] = usage_part[tid * E_ + e]; h[e] = hist_part[tid * E_ + e]; }
    float z = z_part[tid];
    #pragma unroll
    for (int off = 32; off > 0; off >>= 1) {
        #pragma unroll
        for (int e = 0; e < E_; e++) {
            u[e] += __shfl_down(u[e], off);
            h[e] += __shfl_down(h[e], off);
        }
        z += __shfl_down(z, off);
    }
    if ((tid & 63) == 0) {
        #pragma unroll
        for (int e = 0; e < E_; e++) { atomicAdd(&s_u[e], u[e]); atomicAdd(&s_h[e], h[e]); }
        atomicAdd(&s_z, z);
    }
    __syncthreads();
    if (tid == 0) {
        int o = 0, nt = 0;
        for (int e = 0; e < E_; e++) {
            int c = s_h[e];
            counts[e] = c; offsets[e] = o; o += c;
            for (int m0 = 0; m0 < c; m0 += 128) tile_list[1 + nt++] = (m0 << 8) | e;
        }
        tile_list[0] = nt;
        float uu[E_], mean = 0.f;
        for (int e = 0; e < E_; e++) { uu[e] = s_u[e] / (float)NTOK; mean += uu[e]; }
        mean /= (float)E_;
        float var = 0.f;
        for (int e = 0; e < E_; e++) { float d = uu[e] - mean; var += d * d; }
        var /= (float)E_;
        out_scalars[0] = var / (mean * mean + 1e-8f) * (float)E_ * 0.01f;  // lb_loss
        out_scalars[1] = (s_z / (float)NTOK) * 0.001f;                      // z_loss
    }
}

// ---------------- build compact per-expert assignment lists ----------------
__global__ __launch_bounds__(256) void k_fill(
    const int* __restrict__ tk_idx, const float* __restrict__ tk_w,
    const int* __restrict__ offsets, int* __restrict__ cursors,
    int* __restrict__ assign_token, float* __restrict__ assign_weight)
{
    __shared__ int l_cnt[E_];
    __shared__ int l_base[E_];
    int tid = threadIdx.x;
    if (tid < E_) l_cnt[tid] = 0;
    __syncthreads();
    int t = blockIdx.x * 256 + tid;
    int e0 = tk_idx[t * 2 + 0], e1 = tk_idx[t * 2 + 1];
    int r0 = atomicAdd(&l_cnt[e0], 1);
    int r1 = atomicAdd(&l_cnt[e1], 1);
    __syncthreads();
    if (tid < E_) l_base[tid] = atomicAdd(&cursors[tid], l_cnt[tid]);
    __syncthreads();
    int row0 = offsets[e0] + l_base[e0] + r0;
    int row1 = offsets[e1] + l_base[e1] + r1;
    assign_token[row0] = t; assign_weight[row0] = tk_w[t * 2 + 0];
    assign_token[row1] = t; assign_weight[row1] = tk_w[t * 2 + 1];
}

// ---------------- GEMM1: h = gelu(gather(x) @ W1[e] + b1[e]) ----------------
// 1D grid, XCD-swizzled: xcd=bid&7, j=bid>>3, nx=j/17, mloc=j%17, mt=xcd*17+mloc.
// m-siblings sharing the w1t slice (e,n0) run adjacently on ONE XCD -> L2 reuse.
__global__ __launch_bounds__(256) void k_gemm1(
    const u16* __restrict__ xb, const u16* __restrict__ w1t,
    const float* __restrict__ b1,
    const int* __restrict__ counts, const int* __restrict__ offsets,
    const int* __restrict__ tile_list,
    const int* __restrict__ assign_token, u16* __restrict__ h)
{
    int bid = blockIdx.x;
    int xcd = bid & 7;
    int j = bid >> 3;
    int nx = j / 17;
    int mt = xcd * 17 + (j % 17);
    int nt = tile_list[0];
    if (mt >= nt) return;
    int packed = tile_list[1 + mt];
    int e = packed & 0xff;
    int m0 = packed >> 8;
    int cnt = counts[e];
    int off = offsets[e];
    int n0 = nx * 128;

    __shared__ __align__(16) u16 SM[16384];   // As dbuf @0, Bs dbuf @8192 (u16 idx)
    char* smb = (char*)SM;

    int tid = threadIdx.x;
    int w = tid >> 6, lane = tid & 63;
    int rA = lane >> 2;
    // XOR-swizzled k-chunk for staging: lane (rA,c) loads global chunk c^(rA&3)
    int colk = ((lane & 3) ^ (rA & 3)) * 8;
    int r0 = (w * 2 + 0) * 16 + rA;
    int r1 = (w * 2 + 1) * 16 + rA;

    int c0b = __builtin_amdgcn_readfirstlane((w * 2 + 0) * 1024);
    int c1b = __builtin_amdgcn_readfirstlane((w * 2 + 1) * 1024);

    int g0 = m0 + r0; if (g0 > cnt - 1) g0 = cnt - 1;
    int g1 = m0 + r1; if (g1 > cnt - 1) g1 = cnt - 1;
    const u16* agp0 = xb + (size_t)assign_token[off + g0] * D_ + colk;
    const u16* agp1 = xb + (size_t)assign_token[off + g1] * D_ + colk;
    const u16* bgp0 = w1t + ((size_t)e * F_ + n0 + r0) * D_ + colk;
    const u16* bgp1 = w1t + ((size_t)e * F_ + n0 + r1) * D_ + colk;

    f32x4 acc[4][4];
    #pragma unroll
    for (int i = 0; i < 4; i++)
        #pragma unroll
        for (int j2 = 0; j2 < 4; j2++) acc[i][j2] = (f32x4){0.f, 0.f, 0.f, 0.f};

    int wm = (w >> 1) * 64, wn = (w & 1) * 64;
    int fm = lane & 15;
    int slot = ((lane >> 4) ^ (fm & 3)) * 8;   // swizzled fragment slot

    #define STAGE1(buf, kk) do { \
        async16(agp0 + (kk), smb + (buf) * 8192 + c0b); \
        async16(agp1 + (kk), smb + (buf) * 8192 + c1b); \
        async16(bgp0 + (kk), smb + 16384 + (buf) * 8192 + c0b); \
        async16(bgp1 + (kk), smb + 16384 + (buf) * 8192 + c1b); \
    } while (0)
    #define COMPUTE1(buf) do { \
        const u16* Ab = SM + (buf) * 4096; \
        const u16* Bb = SM + 8192 + (buf) * 4096; \
        bf16x8 af[4], bfr[4]; \
        _Pragma("unroll") \
        for (int i = 0; i < 4; i++) af[i] = *(const bf16x8*)&Ab[(wm + i * 16 + fm) * 32 + slot]; \
        _Pragma("unroll") \
        for (int j2 = 0; j2 < 4; j2++) bfr[j2] = *(const bf16x8*)&Bb[(wn + j2 * 16 + fm) * 32 + slot]; \
        _Pragma("unroll") \
        for (int i = 0; i < 4; i++) \
            _Pragma("unroll") \
            for (int j2 = 0; j2 < 4; j2++) \
                acc[i][j2] = __builtin_amdgcn_mfma_f32_16x16x32_bf16(af[i], bfr[j2], acc[i][j2], 0, 0, 0); \
    } while (0)

    STAGE1(0, 0);
    __syncthreads();
    for (int kk = 0; kk < D_; kk += 64) {
        STAGE1(1, kk + 32);
        COMPUTE1(0);
        __syncthreads();
        if (kk + 64 < D_) STAGE1(0, kk + 64);
        COMPUTE1(1);
        __syncthreads();
    }
    #undef STAGE1
    #undef COMPUTE1

    // ---- epilogue: gelu+cvt -> per-wave swizzled LDS tile -> coalesced uint4 stores ----
    int rbase = (lane >> 4) * 4;
    u16* tb = SM + w * 4096;          // 64x64 u16 (8 KB), XOR-swizzled by (m&7)
    float biasv[4];
    #pragma unroll
    for (int j2 = 0; j2 < 4; j2++) biasv[j2] = b1[e * F_ + n0 + wn + j2 * 16 + fm];
    #pragma unroll
    for (int i = 0; i < 4; i++)
        #pragma unroll
        for (int j2 = 0; j2 < 4; j2++)
            #pragma unroll
            for (int r = 0; r < 4; r++) {
                int m_l = i * 16 + rbase + r;
                int f_l = j2 * 16 + fm;
                u16 q = f2bf(gelu_f(acc[i][j2][r] + biasv[j2]));
                tb[m_l * 64 + ((((f_l >> 3) ^ (m_l & 7)) << 3) | (f_l & 7))] = q;
            }
    __syncthreads();
    #pragma unroll
    for (int s = 0; s < 8; s++) {
        int m_l = s * 8 + (lane >> 3);
        int c = lane & 7;
        uint4 vv = *(const uint4*)&tb[m_l * 64 + ((c ^ (m_l & 7)) << 3)];
        int m = m0 + wm + m_l;
        if (m < cnt)
            *(uint4*)&h[(size_t)(off + m) * F_ + n0 + wn + c * 8] = vv;
    }
}

// ---------------- GEMM2: out[token] += (h @ W2[e] + b2[e]) * weight (atomic combine) ----------------
// 1D grid, XCD-swizzled: xcd=bid&7, j=bid>>3, mloc=j/6, nx=j%6, mt=xcd*17+mloc.
// The 6 n-siblings of each m-tile run adjacently on ONE XCD -> h slice L2-resident.
__global__ __launch_bounds__(256) void k_gemm2(
    const u16* __restrict__ h, const u16* __restrict__ w2t,
    const float* __restrict__ b2,
    const int* __restrict__ counts, const int* __restrict__ offsets,
    const int* __restrict__ tile_list,
    const int* __restrict__ assign_token, const float* __restrict__ assign_weight,
    float* __restrict__ out)
{
    int bid = blockIdx.x;
    int xcd = bid & 7;
    int j = bid >> 3;
    int nx = j % 6;
    int mt = xcd * 17 + (j / 6);
    int nt = tile_list[0];
    if (mt >= nt) return;
    int packed = tile_list[1 + mt];
    int e = packed & 0xff;
    int m0 = packed >> 8;
    int cnt = counts[e];
    int off = offsets[e];
    int n0 = nx * 128;

    __shared__ __align__(16) u16 SM[16384];
    char* smb = (char*)SM;

    int tid = threadIdx.x;
    int w = tid >> 6, lane = tid & 63;
    int rA = lane >> 2;
    int colk = ((lane & 3) ^ (rA & 3)) * 8;
    int r0 = (w * 2 + 0) * 16 + rA;
    int r1 = (w * 2 + 1) * 16 + rA;

    int c0b = __builtin_amdgcn_readfirstlane((w * 2 + 0) * 1024);
    int c1b = __builtin_amdgcn_readfirstlane((w * 2 + 1) * 1024);

    // rows beyond cnt over-read hbuf slack rows (allocated), masked at store
    const u16* agp0 = h + (size_t)(off + m0 + r0) * F_ + colk;
    const u16* agp1 = h + (size_t)(off + m0 + r1) * F_ + colk;
    const u16* bgp0 = w2t + ((size_t)e * D_ + n0 + r0) * F_ + colk;
    const u16* bgp1 = w2t + ((size_t)e * D_ + n0 + r1) * F_ + colk;

    f32x4 acc[4][4];
    #pragma unroll
    for (int i = 0; i < 4; i++)
        #pragma unroll
        for (int j2 = 0; j2 < 4; j2++) acc[i][j2] = (f32x4){0.f, 0.f, 0.f, 0.f};

    int wm = (w >> 1) * 64, wn = (w & 1) * 64;
    int fm = lane & 15;
    int slot = ((lane >> 4) ^ (fm & 3)) * 8;

    #define STAGE2(buf, kk) do { \
        async16(agp0 + (kk), smb + (buf) * 8192 + c0b); \
        async16(agp1 + (kk), smb + (buf) * 8192 + c1b); \
        async16(bgp0 + (kk), smb + 16384 + (buf) * 8192 + c0b); \
        async16(bgp1 + (kk), smb + 16384 + (buf) * 8192 + c1b); \
    } while (0)
    #define COMPUTE2(buf) do { \
        const u16* Ab = SM + (buf) * 4096; \
        const u16* Bb = SM + 8192 + (buf) * 4096; \
        bf16x8 af[4], bfr[4]; \
        _Pragma("unroll") \
        for (int i = 0; i < 4; i++) af[i] = *(const bf16x8*)&Ab[(wm + i * 16 + fm) * 32 + slot]; \
        _Pragma("unroll") \
        for (int j2 = 0; j2 < 4; j2++) bfr[j2] = *(const bf16x8*)&Bb[(wn + j2 * 16 + fm) * 32 + slot]; \
        _Pragma("unroll") \
        for (int i = 0; i < 4; i++) \
            _Pragma("unroll") \
            for (int j2 = 0; j2 < 4; j2++) \
                acc[i][j2] = __builtin_amdgcn_mfma_f32_16x16x32_bf16(af[i], bfr[j2], acc[i][j2], 0, 0, 0); \
    } while (0)

    STAGE2(0, 0);
    __syncthreads();
    for (int kk = 0; kk < F_; kk += 64) {
        STAGE2(1, kk + 32);
        COMPUTE2(0);
        __syncthreads();
        if (kk + 64 < F_) STAGE2(0, kk + 64);
        COMPUTE2(1);
        __syncthreads();
    }
    #undef STAGE2
    #undef COMPUTE2

    int rbase = (lane >> 4) * 4;
    float biasv[4];
    #pragma unroll
    for (int j2 = 0; j2 < 4; j2++) biasv[j2] = b2[e * D_ + n0 + wn + j2 * 16 + fm];
    #pragma unroll
    for (int i = 0; i < 4; i++)
        #pragma unroll
        for (int r = 0; r < 4; r++) {
            int m = m0 + wm + i * 16 + rbase + r;
            if (m < cnt) {
                int t = assign_token[off + m];
                float wg = assign_weight[off + m];
                float* orow = out + (size_t)t * D_ + n0 + wn + fm;
                #pragma unroll
                for (int j2 = 0; j2 < 4; j2++)
                    unsafeAtomicAdd(orow + j2 * 16, (acc[i][j2][r] + biasv[j2]) * wg);
            }
        }
}

extern "C" void kernel_launch(void* const* d_in, const int* in_sizes, int n_in,
                              void* d_out, int out_size, void* d_ws, size_t ws_size,
                              hipStream_t stream)
{
    const float* x  = (const float*)d_in[0];
    const float* Wr = (const float*)d_in[1];
    const float* W1 = (const float*)d_in[2];
    const float* b1 = (const float*)d_in[3];
    const float* W2 = (const float*)d_in[4];
    const float* b2 = (const float*)d_in[5];
    float* out = (float*)d_out;

    char* base = (char*)d_ws;
    size_t o = 0;
    auto alloc = [&](size_t bytes) {
        char* r = base + o;
        o += (bytes + 255) & ~(size_t)255;
        return r;
    };
    int*   counts        = (int*)  alloc(E_ * 4);
    int*   cursors       = (int*)  alloc(E_ * 4);
    int*   offsets       = (int*)  alloc(E_ * 4);
    int*   tile_list     = (int*)  alloc(256 * 4);
    float* usage_part    = (float*)alloc((size_t)RBLK * E_ * 4);
    float* z_part        = (float*)alloc((size_t)RBLK * 4);
    int*   hist_part     = (int*)  alloc((size_t)RBLK * E_ * 4);
    int*   tk_idx        = (int*)  alloc((size_t)NTOK * 2 * 4);
    float* tk_w          = (float*)alloc((size_t)NTOK * 2 * 4);
    int*   assign_token  = (int*)  alloc((size_t)NASSIGN * 4);
    float* assign_weight = (float*)alloc((size_t)NASSIGN * 4);
    u16*   xb            = (u16*)  alloc((size_t)NTOK * D_ * 2);
    u16*   w1t           = (u16*)  alloc((size_t)E_ * F_ * D_ * 2);
    u16*   w2t           = (u16*)  alloc((size_t)E_ * D_ * F_ * 2);
    u16*   hbuf          = (u16*)  alloc((size_t)(NASSIGN + 128) * F_ * 2);  // +128 over-read slack

    hipMemsetAsync(d_out, 0, (size_t)out_size * 4, stream);
    k_init<<<dim3(1), dim3(64), 0, stream>>>(cursors);
    k_cvt_x<<<dim3(NTOK * D_ / 1024), dim3(256), 0, stream>>>(x, xb);
    k_tcvt<<<dim3(F_ / 32, D_ / 32, E_), dim3(256), 0, stream>>>(W1, w1t, D_, F_);
    k_tcvt<<<dim3(D_ / 32, F_ / 32, E_), dim3(256), 0, stream>>>(W2, w2t, F_, D_);
    k_router<<<dim3(RBLK), dim3(256), 0, stream>>>(x, Wr, usage_part, z_part, hist_part, tk_idx, tk_w);
    k_finalize<<<dim3(1), dim3(256), 0, stream>>>(usage_part, z_part, hist_part, counts, offsets,
                                                  tile_list, out + (size_t)NTOK * D_);
    k_fill<<<dim3(FBLK), dim3(256), 0, stream>>>(tk_idx, tk_w, offsets, cursors, assign_token, assign_weight);
    k_gemm1<<<dim3(8 * 17 * (F_ / 128)), dim3(256), 0, stream>>>(xb, w1t, b1, counts, offsets, tile_list,
                                                                 assign_token, hbuf);
    k_gemm2<<<dim3(8 * 17 * (D_ / 128)), dim3(256), 0, stream>>>(hbuf, w2t, b2, counts, offsets, tile_list,
                                                                 assign_token, assign_weight, out);
}